// Round 1
// baseline (809.674 us; speedup 1.0000x reference)
//
#include <hip/hip_runtime.h>

typedef unsigned short ushort;
typedef __bf16 bf16x8 __attribute__((ext_vector_type(8)));
typedef float f32x4 __attribute__((ext_vector_type(4)));
typedef float f4 __attribute__((ext_vector_type(4)));
typedef unsigned short us8 __attribute__((ext_vector_type(8)));
typedef unsigned short us4 __attribute__((ext_vector_type(4)));

#define NPIX 127008   // 8*126*126
#define HDIM 126
#define WDIM 126
#define NB 8

__device__ __forceinline__ float bf2f(ushort u) {
  unsigned v = ((unsigned)u) << 16;
  return __builtin_bit_cast(float, v);
}
__device__ __forceinline__ ushort f2bf(float f) {
  unsigned x = __builtin_bit_cast(unsigned, f);
  x += 0x7fffu + ((x >> 16) & 1u);
  return (ushort)(x >> 16);
}

// ---------------- converts ----------------
__global__ void k_cvt_x(const float* __restrict__ x, ushort* __restrict__ xb, int n8) {
  const int stride = gridDim.x * blockDim.x;
  for (int i = blockIdx.x * blockDim.x + threadIdx.x; i < n8; i += stride) {
    const f4 a = *(const f4*)&x[(size_t)i * 8];
    const f4 b = *(const f4*)&x[(size_t)i * 8 + 4];
    us8 o;
#pragma unroll
    for (int j = 0; j < 4; ++j) { o[j] = f2bf(a[j]); o[4 + j] = f2bf(b[j]); }
    *(us8*)&xb[(size_t)i * 8] = o;
  }
}

// out[n*K+k] = in[k*N+n]  (bf16 transpose of [K][N] -> [N][K])
__global__ void k_cvt_wT(const float* __restrict__ in, ushort* __restrict__ out, int N, int K) {
  const int t = blockIdx.x * 256 + threadIdx.x;
  const int n = t / K, k = t - n * K;
  out[t] = f2bf(in[(size_t)k * N + n]);
}

// ---------------- CPB bias MLP ----------------
__device__ __forceinline__ float frel(int i) {
  const float v = (float)(i - 7) * (8.0f / 7.0f);
  const float a = log1pf(fabsf(v)) * 0.4808983469629878f; // 1/ln(8)
  return v < 0.f ? -a : a;
}

__global__ __launch_bounds__(256) void k_cpb1(const float* __restrict__ w0,
    const float* __restrict__ b0, const float* __restrict__ w1, float* __restrict__ tmp) {
  const int p = blockIdx.x * 4 + (threadIdx.x >> 6);
  const int lane = threadIdx.x & 63;
  if (p >= 225) return;
  const float r0 = frel(p / 15), r1 = frel(p % 15);
  float hv[8];
#pragma unroll
  for (int jj = 0; jj < 8; ++jj) {
    const int j = lane * 8 + jj;
    hv[jj] = fmaxf(0.f, r0 * w0[j] + r1 * w0[512 + j] + b0[j]);
  }
  for (int h = 0; h < 8; ++h) {
    float part = 0.f;
#pragma unroll
    for (int jj = 0; jj < 8; ++jj) part += hv[jj] * w1[(lane * 8 + jj) * 8 + h];
    for (int o = 32; o; o >>= 1) part += __shfl_xor(part, o);
    if (lane == 0) tmp[p * 8 + h] = 16.f / (1.f + __expf(-part));
  }
}

// biasT[h][k][q] = tmp[((aq-ak+7)*15 + (bq-bk+7))*8 + h]
__global__ void k_cpb2(const float* __restrict__ tmp, float* __restrict__ biasT) {
  const int t = blockIdx.x * 256 + threadIdx.x; // 32768
  const int h = t >> 12, k = (t >> 6) & 63, q = t & 63;
  const int d0 = (q >> 3) - (k >> 3) + 7, d1 = (q & 7) - (k & 7) + 7;
  biasT[t] = tmp[(d0 * 15 + d1) * 8 + h];
}

// ---------------- bf16 MFMA GEMM: C[M,N] = A[M,K=256] * Bt[N,K]^T ----------------
#define GLL(g, l) __builtin_amdgcn_global_load_lds( \
    (const __attribute__((address_space(1))) void*)(g), \
    (__attribute__((address_space(3))) void*)(l), 16, 0, 0)

template <int OUTF>
__global__ __launch_bounds__(256) void k_gemm(const ushort* __restrict__ A,
                                              const ushort* __restrict__ Bt,
                                              void* __restrict__ Cv, int M, int N) {
  constexpr int K = 256;
  __shared__ ushort lsA[128 * 32];
  __shared__ ushort lsB[128 * 32];
  const int tid = threadIdx.x;
  const int wid = tid >> 6, lane = tid & 63;
  const int m0 = blockIdx.x * 128, n0 = blockIdx.y * 128;

  f32x4 acc[4][4];
#pragma unroll
  for (int i = 0; i < 4; ++i)
#pragma unroll
    for (int j = 0; j < 4; ++j) acc[i][j] = 0.f;

  const int srow = tid >> 2, sk = (tid & 3) * 8;
  const int aw = (wid >> 1) * 64, bw = (wid & 1) * 64;
  const int fr = lane & 15, kg = (lane >> 4) * 8;
  char* lA = (char*)lsA + wid * 1024;
  char* lB = (char*)lsB + wid * 1024;

  int ra0 = m0 + srow;      if (ra0 >= M) ra0 = M - 1;
  int ra1 = m0 + srow + 64; if (ra1 >= M) ra1 = M - 1;
  const int rb0 = n0 + srow, rb1 = n0 + srow + 64;

  for (int kt = 0; kt < K; kt += 32) {
    __syncthreads();  // previous tile fully consumed
    GLL(A + (size_t)ra0 * K + kt + sk, lA);
    GLL(A + (size_t)ra1 * K + kt + sk, lA + 4096);
    GLL(Bt + (size_t)rb0 * K + kt + sk, lB);
    GLL(Bt + (size_t)rb1 * K + kt + sk, lB + 4096);
    __syncthreads();  // vmcnt(0) drain at barrier
    bf16x8 af[4], bb[4];
#pragma unroll
    for (int i = 0; i < 4; ++i)
      af[i] = *(const bf16x8*)&lsA[(aw + i * 16 + fr) * 32 + kg];
#pragma unroll
    for (int j = 0; j < 4; ++j)
      bb[j] = *(const bf16x8*)&lsB[(bw + j * 16 + fr) * 32 + kg];
#pragma unroll
    for (int i = 0; i < 4; ++i)
#pragma unroll
      for (int j = 0; j < 4; ++j)
        acc[i][j] = __builtin_amdgcn_mfma_f32_16x16x32_bf16(af[i], bb[j], acc[i][j], 0, 0, 0);
  }

  const int r4 = (lane >> 4) * 4, cc = lane & 15;
#pragma unroll
  for (int i = 0; i < 4; ++i) {
#pragma unroll
    for (int j = 0; j < 4; ++j) {
      const int gc = n0 + bw + j * 16 + cc;
#pragma unroll
      for (int r = 0; r < 4; ++r) {
        const int gr = m0 + aw + i * 16 + r4 + r;
        if (gr < M) {
          if constexpr (OUTF == 0)
            ((ushort*)Cv)[(size_t)gr * N + gc] = f2bf(acc[i][j][r]);
          else
            ((float*)Cv)[(size_t)gr * N + gc] = acc[i][j][r];
        }
      }
    }
  }
}

// ---------------- depthwise 3x3 conv (SAME, zeros) ----------------
__global__ __launch_bounds__(256) void k_conv(const ushort* __restrict__ in,
                                              const float* __restrict__ wdw,
                                              ushort* __restrict__ out) {
  const int e0 = blockIdx.x * 3072; // 32 px * 96 ch-groups
#pragma unroll 1
  for (int it = 0; it < 12; ++it) {
    const int e = e0 + it * 256 + threadIdx.x;
    const int pg = e / 96, cg = e - (e / 96) * 96;
    const int w = pg % WDIM, t2 = pg / WDIM;
    const int h = t2 % HDIM, b = t2 / HDIM;
    const int c0 = cg * 8;
    float acc[8];
#pragma unroll
    for (int j = 0; j < 8; ++j) acc[j] = 0.f;
#pragma unroll
    for (int dy = 0; dy < 3; ++dy) {
      const int hh = h + dy - 1;
      if (hh < 0 || hh >= HDIM) continue;
#pragma unroll
      for (int dx = 0; dx < 3; ++dx) {
        const int ww2 = w + dx - 1;
        if (ww2 < 0 || ww2 >= WDIM) continue;
        const us8 vin = *(const us8*)&in[((size_t)((b * HDIM + hh) * WDIM + ww2)) * 768 + c0];
        const f4 wa = *(const f4*)&wdw[(dy * 3 + dx) * 768 + c0];
        const f4 wb = *(const f4*)&wdw[(dy * 3 + dx) * 768 + c0 + 4];
#pragma unroll
        for (int j = 0; j < 4; ++j) acc[j] += bf2f(vin[j]) * wa[j];
#pragma unroll
        for (int j = 0; j < 4; ++j) acc[4 + j] += bf2f(vin[4 + j]) * wb[j];
      }
    }
    us8 o;
#pragma unroll
    for (int j = 0; j < 8; ++j) o[j] = f2bf(acc[j]);
    *(us8*)&out[(size_t)pg * 768 + c0] = o;
  }
}

// ---------------- LN + bias + l2norm(q,k) + logit-scale + window scatter ----------------
__global__ __launch_bounds__(256) void k_ln(const ushort* __restrict__ post,
    const float* __restrict__ gamma, const float* __restrict__ beta,
    const float* __restrict__ qb, const float* __restrict__ vb,
    const float* __restrict__ scale, ushort* __restrict__ qkvw) {
  const int pix = blockIdx.x * 4 + (threadIdx.x >> 6);
  const int lane = threadIdx.x & 63;
  const ushort* row = post + (size_t)pix * 768;
  float v[3][4];
#pragma unroll
  for (int c = 0; c < 3; ++c) {
    const us4 u = *(const us4*)&row[(lane + 64 * c) * 4];
#pragma unroll
    for (int j = 0; j < 4; ++j) v[c][j] = bf2f(u[j]);
  }
  float s = 0.f;
#pragma unroll
  for (int c = 0; c < 3; ++c)
#pragma unroll
    for (int j = 0; j < 4; ++j) s += v[c][j];
  for (int o = 32; o; o >>= 1) s += __shfl_xor(s, o);
  const float mu = s * (1.f / 768.f);
  float ss = 0.f;
#pragma unroll
  for (int c = 0; c < 3; ++c)
#pragma unroll
    for (int j = 0; j < 4; ++j) { const float d = v[c][j] - mu; ss += d * d; }
  for (int o = 32; o; o >>= 1) ss += __shfl_xor(ss, o);
  const float rs = rsqrtf(ss * (1.f / 768.f) + 1e-5f);

  float y[3][4];
#pragma unroll
  for (int c = 0; c < 3; ++c) {
    const int chb = (lane + 64 * c) * 4;
#pragma unroll
    for (int j = 0; j < 4; ++j)
      y[c][j] = (v[c][j] - mu) * rs * gamma[chb + j] + beta[chb + j];
  }
#pragma unroll
  for (int j = 0; j < 4; ++j) { y[0][j] += qb[lane * 4 + j]; y[2][j] += vb[lane * 4 + j]; }

#pragma unroll
  for (int c = 0; c < 2; ++c) {   // l2norm over each 32-ch head group (8 lanes x 4)
    float g = y[c][0] * y[c][0] + y[c][1] * y[c][1] + y[c][2] * y[c][2] + y[c][3] * y[c][3];
    g += __shfl_xor(g, 1); g += __shfl_xor(g, 2); g += __shfl_xor(g, 4);
    const float rn = rsqrtf(fmaxf(g, 1.55e-5f));
#pragma unroll
    for (int j = 0; j < 4; ++j) y[c][j] *= rn;
  }
  const float ls = __expf(fminf(scale[lane >> 3], 4.60517025f)); // min(scale, ln 100)
#pragma unroll
  for (int j = 0; j < 4; ++j) y[0][j] *= ls;

  // window scatter: padded coords hp=h+1, wp=w+1; win=(hp&15)*16+(wp&15); tok=(hp>>4)*8+(wp>>4)
  const int w = pix % WDIM, t2 = pix / WDIM, h = t2 % HDIM, b = t2 / HDIM;
  const int hp = h + 1, wp = w + 1;
  const int dstrow = (((b << 8) + ((hp & 15) << 4) + (wp & 15)) << 6) + ((hp >> 4) << 3) + (wp >> 4);
  ushort* orow = qkvw + (size_t)dstrow * 768;
#pragma unroll
  for (int c = 0; c < 3; ++c) {
    us4 u;
#pragma unroll
    for (int j = 0; j < 4; ++j) u[j] = f2bf(y[c][j]);
    *(us4*)&orow[(lane + 64 * c) * 4] = u;
  }
}

// ---------------- attention: 1 wave per (window, head) ----------------
__device__ __forceinline__ bool tok_valid(int wh, int ww, int t) {
  const int a = t >> 3, b = t & 7;
  const bool rv = !((wh == 0 && a == 0) || (wh == 15 && a == 7));
  const bool cv = !((ww == 0 && b == 0) || (ww == 15 && b == 7));
  return rv && cv;
}

__global__ __launch_bounds__(64) void k_attn(const ushort* __restrict__ qkvw,
    const float* __restrict__ biasT, ushort* __restrict__ aout) {
  const int u = blockIdx.x;
  const int head = u >> 11, wl = u & 2047;
  const int b = wl >> 8, wh = (wl >> 4) & 15, ww = wl & 15;
  const int lane = threadIdx.x;
  __shared__ float Ks[64][36];
  __shared__ float Vs[64][36];
  const size_t base = (size_t)wl * 64 * 768;
  {
    const bool tv = tok_valid(wh, ww, lane);
    const ushort* kp = qkvw + base + (size_t)lane * 768 + 256 + head * 32;
    const us8 zz = 0;
#pragma unroll
    for (int c = 0; c < 4; ++c) {
      us8 ku = *(const us8*)&kp[c * 8];
      us8 vu = *(const us8*)&kp[256 + c * 8];
      ku = tv ? ku : zz; vu = tv ? vu : zz;  // zero pad rows (keeps NaN-poison out)
      f4 klo, khi, vlo, vhi;
#pragma unroll
      for (int j = 0; j < 4; ++j) {
        klo[j] = bf2f(ku[j]); khi[j] = bf2f(ku[4 + j]);
        vlo[j] = bf2f(vu[j]); vhi[j] = bf2f(vu[4 + j]);
      }
      *(f4*)&Ks[lane][c * 8] = klo; *(f4*)&Ks[lane][c * 8 + 4] = khi;
      *(f4*)&Vs[lane][c * 8] = vlo; *(f4*)&Vs[lane][c * 8 + 4] = vhi;
    }
  }
  float q[32];
  {
    const ushort* qp = qkvw + base + (size_t)lane * 768 + head * 32;
#pragma unroll
    for (int c = 0; c < 4; ++c) {
      const us8 uq = *(const us8*)&qp[c * 8];
#pragma unroll
      for (int j = 0; j < 8; ++j) q[c * 8 + j] = bf2f(uq[j]);
    }
  }
  __syncthreads();
  const float* bt = biasT + (head << 12);
  float m = -1e30f, denom = 0.f, O[32];
#pragma unroll
  for (int d = 0; d < 32; ++d) O[d] = 0.f;
#pragma unroll 1
  for (int c = 0; c < 4; ++c) {   // online softmax over 4 chunks of 16 keys
    float sv[16];
#pragma unroll
    for (int kk = 0; kk < 16; ++kk) {
      const int k = c * 16 + kk;
      float d0 = 0.f, d1 = 0.f, d2 = 0.f, d3 = 0.f;
#pragma unroll
      for (int x = 0; x < 32; x += 4) {
        const f4 kv = *(const f4*)&Ks[k][x];
        d0 += q[x] * kv[0]; d1 += q[x + 1] * kv[1];
        d2 += q[x + 2] * kv[2]; d3 += q[x + 3] * kv[3];
      }
      const float bias = bt[(k << 6) + lane];
      sv[kk] = tok_valid(wh, ww, k) ? ((d0 + d1) + (d2 + d3)) + bias : -1e30f;
    }
    float mc = sv[0];
#pragma unroll
    for (int kk = 1; kk < 16; ++kk) mc = fmaxf(mc, sv[kk]);
    const float mn = fmaxf(m, mc);
    const float scl = __expf(m - mn);
    denom *= scl;
#pragma unroll
    for (int d = 0; d < 32; ++d) O[d] *= scl;
#pragma unroll
    for (int kk = 0; kk < 16; ++kk) {
      const int k = c * 16 + kk;
      const float p = __expf(sv[kk] - mn);
      denom += p;
#pragma unroll
      for (int x = 0; x < 32; x += 4) {
        const f4 vv = *(const f4*)&Vs[k][x];
        O[x] += p * vv[0]; O[x + 1] += p * vv[1];
        O[x + 2] += p * vv[2]; O[x + 3] += p * vv[3];
      }
    }
    m = mn;
  }
  if (tok_valid(wh, ww, lane)) {
    const float inv = 1.f / denom;
    const int a = lane >> 3, b2 = lane & 7;
    const int h = a * 16 + wh - 1, w2 = b2 * 16 + ww - 1;
    ushort* op = aout + ((size_t)((b * HDIM + h) * WDIM + w2)) * 256 + head * 32;
#pragma unroll
    for (int c = 0; c < 4; ++c) {
      us8 o;
#pragma unroll
      for (int j = 0; j < 8; ++j) o[j] = f2bf(O[c * 8 + j] * inv);
      *(us8*)&op[c * 8] = o;
    }
  }
}

// ---------------- launch ----------------
extern "C" void kernel_launch(void* const* d_in, const int* in_sizes, int n_in,
                              void* d_out, int out_size, void* d_ws, size_t ws_size,
                              hipStream_t stream) {
  (void)in_sizes; (void)n_in; (void)out_size; (void)ws_size;
  const float* x      = (const float*)d_in[0];
  const float* w_qkv  = (const float*)d_in[1];
  const float* w_dw   = (const float*)d_in[2];
  const float* ln_g   = (const float*)d_in[3];
  const float* ln_b   = (const float*)d_in[4];
  const float* q_bias = (const float*)d_in[5];
  const float* v_bias = (const float*)d_in[6];
  const float* scale  = (const float*)d_in[7];
  const float* cpb_w0 = (const float*)d_in[8];
  const float* cpb_b0 = (const float*)d_in[9];
  const float* cpb_w1 = (const float*)d_in[10];
  const float* w_proj = (const float*)d_in[11];
  float* out = (float*)d_out;

  char* ws = (char*)d_ws;
  const size_t R1 = (size_t)131072 * 768 * 2;  // QKVw (window-padded) / qkv_pre
  const size_t R2 = (size_t)NPIX * 768 * 2;    // xb / qkv_post / attn_out
  ushort* reg1   = (ushort*)ws;
  ushort* reg2   = (ushort*)(ws + R1);
  ushort* wqkvT  = (ushort*)(ws + R1 + R2);
  ushort* wprojT = (ushort*)(ws + R1 + R2 + (size_t)768 * 256 * 2);
  float*  cpbtmp = (float*)(ws + R1 + R2 + (size_t)768 * 256 * 2 + (size_t)256 * 256 * 2);
  float*  biasT  = (float*)(ws + R1 + R2 + (size_t)768 * 256 * 2 + (size_t)256 * 256 * 2 + 8192);

  k_cvt_x<<<2048, 256, 0, stream>>>(x, reg2, NPIX * 256 / 8);
  k_cvt_wT<<<768, 256, 0, stream>>>(w_qkv, wqkvT, 768, 256);
  k_cvt_wT<<<256, 256, 0, stream>>>(w_proj, wprojT, 256, 256);
  k_cpb1<<<57, 256, 0, stream>>>(cpb_w0, cpb_b0, cpb_w1, cpbtmp);
  k_cpb2<<<128, 256, 0, stream>>>(cpbtmp, biasT);
  { dim3 g(993, 6); k_gemm<0><<<g, 256, 0, stream>>>(reg2, wqkvT, reg1, NPIX, 768); }
  k_conv<<<3969, 256, 0, stream>>>(reg1, w_dw, reg2);
  k_ln<<<31752, 256, 0, stream>>>(reg2, ln_g, ln_b, q_bias, v_bias, scale, reg1);
  k_attn<<<16384, 64, 0, stream>>>(reg1, biasT, reg2);
  { dim3 g(993, 2); k_gemm<1><<<g, 256, 0, stream>>>(reg2, wprojT, out, NPIX, 256); }
}

// Round 5
// 659.892 us; speedup vs baseline: 1.2270x; 1.2270x over previous
//
#include <hip/hip_runtime.h>

typedef unsigned short ushort;
typedef __bf16 bf16x8 __attribute__((ext_vector_type(8)));
typedef float f32x4 __attribute__((ext_vector_type(4)));
typedef float f4 __attribute__((ext_vector_type(4)));
typedef unsigned short us8 __attribute__((ext_vector_type(8)));
typedef unsigned short us4 __attribute__((ext_vector_type(4)));

#define NPIX 127008   // 8*126*126
#define HDIM 126
#define WDIM 126

__device__ __forceinline__ float bf2f(ushort u) {
  unsigned v = ((unsigned)u) << 16;
  return __builtin_bit_cast(float, v);
}
__device__ __forceinline__ ushort f2bf(float f) {
  unsigned x = __builtin_bit_cast(unsigned, f);
  x += 0x7fffu + ((x >> 16) & 1u);
  return (ushort)(x >> 16);
}

// ---------------- converts ----------------
__global__ void k_cvt_x(const float* __restrict__ x, ushort* __restrict__ xb, int n8) {
  const int stride = gridDim.x * blockDim.x;
  for (int i = blockIdx.x * blockDim.x + threadIdx.x; i < n8; i += stride) {
    const f4 a = *(const f4*)&x[(size_t)i * 8];
    const f4 b = *(const f4*)&x[(size_t)i * 8 + 4];
    us8 o;
#pragma unroll
    for (int j = 0; j < 4; ++j) { o[j] = f2bf(a[j]); o[4 + j] = f2bf(b[j]); }
    *(us8*)&xb[(size_t)i * 8] = o;
  }
}

__global__ void k_cvt_wT(const float* __restrict__ in, ushort* __restrict__ out, int N, int K) {
  const int t = blockIdx.x * 256 + threadIdx.x;
  const int n = t / K, k = t - n * K;
  out[t] = f2bf(in[(size_t)k * N + n]);
}

// ---------------- CPB bias MLP ----------------
__device__ __forceinline__ float frel(int i) {
  const float v = (float)(i - 7) * (8.0f / 7.0f);
  const float a = log1pf(fabsf(v)) * 0.4808983469629878f; // 1/ln(8)
  return v < 0.f ? -a : a;
}

__global__ __launch_bounds__(256) void k_cpb1(const float* __restrict__ w0,
    const float* __restrict__ b0, const float* __restrict__ w1, float* __restrict__ tmp) {
  const int p = blockIdx.x * 4 + (threadIdx.x >> 6);
  const int lane = threadIdx.x & 63;
  if (p >= 225) return;
  const float r0 = frel(p / 15), r1 = frel(p % 15);
  float hv[8];
#pragma unroll
  for (int jj = 0; jj < 8; ++jj) {
    const int j = lane * 8 + jj;
    hv[jj] = fmaxf(0.f, r0 * w0[j] + r1 * w0[512 + j] + b0[j]);
  }
  for (int h = 0; h < 8; ++h) {
    float part = 0.f;
#pragma unroll
    for (int jj = 0; jj < 8; ++jj) part += hv[jj] * w1[(lane * 8 + jj) * 8 + h];
    for (int o = 32; o; o >>= 1) part += __shfl_xor(part, o);
    if (lane == 0) tmp[p * 8 + h] = 16.f / (1.f + __expf(-part));
  }
}

__global__ void k_cpb2(const float* __restrict__ tmp, float* __restrict__ biasT) {
  const int t = blockIdx.x * 256 + threadIdx.x; // 32768
  const int h = t >> 12, k = (t >> 6) & 63, q = t & 63;
  const int d0 = (q >> 3) - (k >> 3) + 7, d1 = (q & 7) - (k & 7) + 7;
  biasT[t] = tmp[(d0 * 15 + d1) * 8 + h];
}

// ---------------- bf16 MFMA GEMM: C[M,N] = A[M,K=256] * Bt[N,K]^T ----------------
#define GLL(g, l) __builtin_amdgcn_global_load_lds( \
    (const __attribute__((address_space(1))) void*)(g), \
    (__attribute__((address_space(3))) void*)(l), 16, 0, 0)

template <int OUTF>
__global__ __launch_bounds__(256) void k_gemm(const ushort* __restrict__ A,
                                              const ushort* __restrict__ Bt,
                                              void* __restrict__ Cv, int M, int N) {
  constexpr int K = 256;
  __shared__ ushort lsA[128 * 32];
  __shared__ ushort lsB[128 * 32];
  const int tid = threadIdx.x;
  const int wid = tid >> 6, lane = tid & 63;
  const int m0 = blockIdx.x * 128, n0 = blockIdx.y * 128;

  f32x4 acc[4][4];
#pragma unroll
  for (int i = 0; i < 4; ++i)
#pragma unroll
    for (int j = 0; j < 4; ++j) acc[i][j] = 0.f;

  const int srow = tid >> 2, sk = (tid & 3) * 8;
  const int aw = (wid >> 1) * 64, bw = (wid & 1) * 64;
  const int fr = lane & 15, kg = (lane >> 4) * 8;
  char* lA = (char*)lsA + wid * 1024;
  char* lB = (char*)lsB + wid * 1024;

  int ra0 = m0 + srow;      if (ra0 >= M) ra0 = M - 1;
  int ra1 = m0 + srow + 64; if (ra1 >= M) ra1 = M - 1;
  const int rb0 = n0 + srow, rb1 = n0 + srow + 64;

  for (int kt = 0; kt < K; kt += 32) {
    __syncthreads();
    GLL(A + (size_t)ra0 * K + kt + sk, lA);
    GLL(A + (size_t)ra1 * K + kt + sk, lA + 4096);
    GLL(Bt + (size_t)rb0 * K + kt + sk, lB);
    GLL(Bt + (size_t)rb1 * K + kt + sk, lB + 4096);
    __syncthreads();
    bf16x8 af[4], bb[4];
#pragma unroll
    for (int i = 0; i < 4; ++i)
      af[i] = *(const bf16x8*)&lsA[(aw + i * 16 + fr) * 32 + kg];
#pragma unroll
    for (int j = 0; j < 4; ++j)
      bb[j] = *(const bf16x8*)&lsB[(bw + j * 16 + fr) * 32 + kg];
#pragma unroll
    for (int i = 0; i < 4; ++i)
#pragma unroll
      for (int j = 0; j < 4; ++j)
        acc[i][j] = __builtin_amdgcn_mfma_f32_16x16x32_bf16(af[i], bb[j], acc[i][j], 0, 0, 0);
  }

  const int r4 = (lane >> 4) * 4, cc = lane & 15;
#pragma unroll
  for (int i = 0; i < 4; ++i) {
#pragma unroll
    for (int j = 0; j < 4; ++j) {
      const int gc = n0 + bw + j * 16 + cc;
#pragma unroll
      for (int r = 0; r < 4; ++r) {
        const int gr = m0 + aw + i * 16 + r4 + r;
        if (gr < M) {
          if constexpr (OUTF == 0)
            ((ushort*)Cv)[(size_t)gr * N + gc] = f2bf(acc[i][j][r]);
          else
            ((float*)Cv)[(size_t)gr * N + gc] = acc[i][j][r];
        }
      }
    }
  }
}

// ---------------- depthwise 3x3 conv (SAME, zeros) ----------------
__global__ __launch_bounds__(256) void k_conv(const ushort* __restrict__ in,
                                              const float* __restrict__ wdw,
                                              ushort* __restrict__ out) {
  const int e0 = blockIdx.x * 3072;
#pragma unroll 1
  for (int it = 0; it < 12; ++it) {
    const int e = e0 + it * 256 + threadIdx.x;
    const int pg = e / 96, cg = e - (e / 96) * 96;
    const int w = pg % WDIM, t2 = pg / WDIM;
    const int h = t2 % HDIM, b = t2 / HDIM;
    const int c0 = cg * 8;
    float acc[8];
#pragma unroll
    for (int j = 0; j < 8; ++j) acc[j] = 0.f;
#pragma unroll
    for (int dy = 0; dy < 3; ++dy) {
      const int hh = h + dy - 1;
      if (hh < 0 || hh >= HDIM) continue;
#pragma unroll
      for (int dx = 0; dx < 3; ++dx) {
        const int ww2 = w + dx - 1;
        if (ww2 < 0 || ww2 >= WDIM) continue;
        const us8 vin = *(const us8*)&in[((size_t)((b * HDIM + hh) * WDIM + ww2)) * 768 + c0];
        const f4 wa = *(const f4*)&wdw[(dy * 3 + dx) * 768 + c0];
        const f4 wb = *(const f4*)&wdw[(dy * 3 + dx) * 768 + c0 + 4];
#pragma unroll
        for (int j = 0; j < 4; ++j) acc[j] += bf2f(vin[j]) * wa[j];
#pragma unroll
        for (int j = 0; j < 4; ++j) acc[4 + j] += bf2f(vin[4 + j]) * wb[j];
      }
    }
    us8 o;
#pragma unroll
    for (int j = 0; j < 8; ++j) o[j] = f2bf(acc[j]);
    *(us8*)&out[(size_t)pg * 768 + c0] = o;
  }
}

// ---------------- LN + bias + l2norm(q,k) + logit-scale + window scatter ----------------
__global__ __launch_bounds__(256) void k_ln(const ushort* __restrict__ post,
    const float* __restrict__ gamma, const float* __restrict__ beta,
    const float* __restrict__ qb, const float* __restrict__ vb,
    const float* __restrict__ scale, ushort* __restrict__ qkvw) {
  const int pix = blockIdx.x * 4 + (threadIdx.x >> 6);
  const int lane = threadIdx.x & 63;
  const ushort* row = post + (size_t)pix * 768;
  float v[3][4];
#pragma unroll
  for (int c = 0; c < 3; ++c) {
    const us4 u = *(const us4*)&row[(lane + 64 * c) * 4];
#pragma unroll
    for (int j = 0; j < 4; ++j) v[c][j] = bf2f(u[j]);
  }
  float s = 0.f;
#pragma unroll
  for (int c = 0; c < 3; ++c)
#pragma unroll
    for (int j = 0; j < 4; ++j) s += v[c][j];
  for (int o = 32; o; o >>= 1) s += __shfl_xor(s, o);
  const float mu = s * (1.f / 768.f);
  float ss = 0.f;
#pragma unroll
  for (int c = 0; c < 3; ++c)
#pragma unroll
    for (int j = 0; j < 4; ++j) { const float d = v[c][j] - mu; ss += d * d; }
  for (int o = 32; o; o >>= 1) ss += __shfl_xor(ss, o);
  const float rs = rsqrtf(ss * (1.f / 768.f) + 1e-5f);

  float y[3][4];
#pragma unroll
  for (int c = 0; c < 3; ++c) {
    const int chb = (lane + 64 * c) * 4;
#pragma unroll
    for (int j = 0; j < 4; ++j)
      y[c][j] = (v[c][j] - mu) * rs * gamma[chb + j] + beta[chb + j];
  }
#pragma unroll
  for (int j = 0; j < 4; ++j) { y[0][j] += qb[lane * 4 + j]; y[2][j] += vb[lane * 4 + j]; }

#pragma unroll
  for (int c = 0; c < 2; ++c) {
    float g = y[c][0] * y[c][0] + y[c][1] * y[c][1] + y[c][2] * y[c][2] + y[c][3] * y[c][3];
    g += __shfl_xor(g, 1); g += __shfl_xor(g, 2); g += __shfl_xor(g, 4);
    const float rn = rsqrtf(fmaxf(g, 1.55e-5f));
#pragma unroll
    for (int j = 0; j < 4; ++j) y[c][j] *= rn;
  }
  const float ls = __expf(fminf(scale[lane >> 3], 4.60517025f));
#pragma unroll
  for (int j = 0; j < 4; ++j) y[0][j] *= ls;

  const int w = pix % WDIM, t2 = pix / WDIM, h = t2 % HDIM, b = t2 / HDIM;
  const int hp = h + 1, wp = w + 1;
  const int dstrow = (((b << 8) + ((hp & 15) << 4) + (wp & 15)) << 6) + ((hp >> 4) << 3) + (wp >> 4);
  ushort* orow = qkvw + (size_t)dstrow * 768;
#pragma unroll
  for (int c = 0; c < 3; ++c) {
    us4 u;
#pragma unroll
    for (int j = 0; j < 4; ++j) u[j] = f2bf(y[c][j]);
    *(us4*)&orow[(lane + 64 * c) * 4] = u;
  }
}

// ---------------- MFMA attention: 4 waves/block, 1 wave per (window, head) ----------------
// S^T = mfma(K,Q): C col = query = lane&15, row = key = (lane>>4)*4+r
__global__ __launch_bounds__(256) void k_attn(const ushort* __restrict__ qkvw,
    const float* __restrict__ biasT, ushort* __restrict__ aout) {
  __shared__ __align__(16) ushort Pq[4][64][72]; // P[q][key], stride 144B (16B-mult)
  __shared__ __align__(16) ushort Vs[4][64][32]; // V[key][d], natural layout
  const int wid = threadIdx.x >> 6, lane = threadIdx.x & 63;
  const int u = blockIdx.x * 4 + wid;
  const int head = u >> 11, wl = u & 2047;
  const int b = wl >> 8, wh = (wl >> 4) & 15, ww = wl & 15;
  const int c = lane & 15, g = lane >> 4;
  const int g4 = g * 4, g8 = g * 8;
  const ushort* wb = qkvw + (size_t)wl * 64 * 768;
  const us8 zz = 0;

  const bool e_r0 = (wh == 0), e_r7 = (wh == 15), e_c0 = (ww == 0), e_c7 = (ww == 15);
#define TOKVALID(t) (!(((e_r0) & (((t) >> 3) == 0)) | ((e_r7) & (((t) >> 3) == 7)) | \
                       ((e_c0) & (((t) & 7) == 0)) | ((e_c7) & (((t) & 7) == 7))))

  // stage V: lane = token. ALL 32 dims (head_dim=32 -> 4 x us8). Rounds 2-4 bug:
  // only d0..15 staged, so Vs cols 16..31 were uninitialized LDS -> NaN via PV.
  // Invalid-token rows zeroed (their global rows are never written = garbage).
  {
    const bool tv = TOKVALID(lane);
    const ushort* vp = wb + (size_t)lane * 768 + 512 + head * 32;
    us8 v0 = *(const us8*)vp;
    us8 v1 = *(const us8*)(vp + 8);
    us8 v2 = *(const us8*)(vp + 16);
    us8 v3 = *(const us8*)(vp + 24);
    v0 = tv ? v0 : zz;
    v1 = tv ? v1 : zz;
    v2 = tv ? v2 : zz;
    v3 = tv ? v3 : zz;
    *(us8*)&Vs[wid][lane][0]  = v0;
    *(us8*)&Vs[wid][lane][8]  = v1;
    *(us8*)&Vs[wid][lane][16] = v2;
    *(us8*)&Vs[wid][lane][24] = v3;
  }

  // QK^T (swapped): A = K fragments (rows=keys), B = Q fragments (cols=queries)
  bf16x8 kf[4], qf[4];
#pragma unroll
  for (int ki = 0; ki < 4; ++ki) {
    const int tk = ki * 16 + c;
    us8 kv = *(const us8*)&wb[(size_t)tk * 768 + 256 + head * 32 + g8];
    kv = TOKVALID(tk) ? kv : zz;
    kf[ki] = __builtin_bit_cast(bf16x8, kv);
  }
#pragma unroll
  for (int qj = 0; qj < 4; ++qj) {
    const int tq = qj * 16 + c;
    us8 qv = *(const us8*)&wb[(size_t)tq * 768 + head * 32 + g8];
    qv = TOKVALID(tq) ? qv : zz;
    qf[qj] = __builtin_bit_cast(bf16x8, qv);
  }

  f32x4 st[4][4];
#pragma unroll
  for (int ki = 0; ki < 4; ++ki)
#pragma unroll
    for (int qj = 0; qj < 4; ++qj)
      st[ki][qj] = __builtin_amdgcn_mfma_f32_16x16x32_bf16(kf[ki], qf[qj], f32x4{0.f,0.f,0.f,0.f}, 0, 0, 0);

  // softmax per query column (q = qj*16 + c), keys split over lane>>4 groups
  const float* bt = biasT + (head << 12);
#pragma unroll
  for (int qj = 0; qj < 4; ++qj) {
    const int q = qj * 16 + c;
    float s[16];
#pragma unroll
    for (int ki = 0; ki < 4; ++ki)
#pragma unroll
      for (int r = 0; r < 4; ++r) {
        const int key = ki * 16 + g4 + r;
        const float bias = bt[(key << 6) + q];
        s[ki * 4 + r] = TOKVALID(key) ? st[ki][qj][r] + bias : -1e30f;
      }
    float m = s[0];
#pragma unroll
    for (int i = 1; i < 16; ++i) m = fmaxf(m, s[i]);
    m = fmaxf(m, __shfl_xor(m, 16));
    m = fmaxf(m, __shfl_xor(m, 32));
    float den = 0.f;
#pragma unroll
    for (int i = 0; i < 16; ++i) { s[i] = __expf(s[i] - m); den += s[i]; }
    den += __shfl_xor(den, 16);
    den += __shfl_xor(den, 32);
    const float inv = 1.f / den;
#pragma unroll
    for (int ki = 0; ki < 4; ++ki) {
      us4 pk;
#pragma unroll
      for (int r = 0; r < 4; ++r) pk[r] = f2bf(s[ki * 4 + r] * inv);
      *(us4*)&Pq[wid][q][ki * 16 + g4] = pk;
    }
  }
  __syncthreads();

  // PV: O[q][d] = P[q][k] * V[k][d]; A = P frags (b128), B = V frags (scalar gather)
  f32x4 ao[4][2];
#pragma unroll
  for (int qi = 0; qi < 4; ++qi)
#pragma unroll
    for (int di = 0; di < 2; ++di) ao[qi][di] = 0.f;
#pragma unroll
  for (int kc = 0; kc < 2; ++kc) {
    bf16x8 af[4];
#pragma unroll
    for (int qi = 0; qi < 4; ++qi)
      af[qi] = __builtin_bit_cast(bf16x8, *(const us8*)&Pq[wid][qi * 16 + c][kc * 32 + g8]);
#pragma unroll
    for (int di = 0; di < 2; ++di) {
      us8 bv;
#pragma unroll
      for (int j = 0; j < 8; ++j) bv[j] = Vs[wid][kc * 32 + g8 + j][di * 16 + c];
      const bf16x8 bb = __builtin_bit_cast(bf16x8, bv);
#pragma unroll
      for (int qi = 0; qi < 4; ++qi)
        ao[qi][di] = __builtin_amdgcn_mfma_f32_16x16x32_bf16(af[qi], bb, ao[qi][di], 0, 0, 0);
    }
  }

  // store: C col = d = di*16+c, row = q = qi*16+g4+r
#pragma unroll
  for (int qi = 0; qi < 4; ++qi)
#pragma unroll
    for (int r = 0; r < 4; ++r) {
      const int q = qi * 16 + g4 + r;
      if (TOKVALID(q)) {
        const int h = (q >> 3) * 16 + wh - 1, w2 = (q & 7) * 16 + ww - 1;
        ushort* op = aout + ((size_t)((b * HDIM + h) * WDIM + w2)) * 256 + head * 32;
        op[c] = f2bf(ao[qi][0][r]);
        op[16 + c] = f2bf(ao[qi][1][r]);
      }
    }
#undef TOKVALID
}

// ---------------- launch ----------------
extern "C" void kernel_launch(void* const* d_in, const int* in_sizes, int n_in,
                              void* d_out, int out_size, void* d_ws, size_t ws_size,
                              hipStream_t stream) {
  (void)in_sizes; (void)n_in; (void)out_size; (void)ws_size;
  const float* x      = (const float*)d_in[0];
  const float* w_qkv  = (const float*)d_in[1];
  const float* w_dw   = (const float*)d_in[2];
  const float* ln_g   = (const float*)d_in[3];
  const float* ln_b   = (const float*)d_in[4];
  const float* q_bias = (const float*)d_in[5];
  const float* v_bias = (const float*)d_in[6];
  const float* scale  = (const float*)d_in[7];
  const float* cpb_w0 = (const float*)d_in[8];
  const float* cpb_b0 = (const float*)d_in[9];
  const float* cpb_w1 = (const float*)d_in[10];
  const float* w_proj = (const float*)d_in[11];
  float* out = (float*)d_out;

  char* ws = (char*)d_ws;
  const size_t R1 = (size_t)131072 * 768 * 2;
  const size_t R2 = (size_t)NPIX * 768 * 2;
  ushort* reg1   = (ushort*)ws;
  ushort* reg2   = (ushort*)(ws + R1);
  ushort* wqkvT  = (ushort*)(ws + R1 + R2);
  ushort* wprojT = (ushort*)(ws + R1 + R2 + (size_t)768 * 256 * 2);
  float*  cpbtmp = (float*)(ws + R1 + R2 + (size_t)768 * 256 * 2 + (size_t)256 * 256 * 2);
  float*  biasT  = (float*)(ws + R1 + R2 + (size_t)768 * 256 * 2 + (size_t)256 * 256 * 2 + 8192);

  k_cvt_x<<<2048, 256, 0, stream>>>(x, reg2, NPIX * 256 / 8);
  k_cvt_wT<<<768, 256, 0, stream>>>(w_qkv, wqkvT, 768, 256);
  k_cvt_wT<<<256, 256, 0, stream>>>(w_proj, wprojT, 256, 256);
  k_cpb1<<<57, 256, 0, stream>>>(cpb_w0, cpb_b0, cpb_w1, cpbtmp);
  k_cpb2<<<128, 256, 0, stream>>>(cpbtmp, biasT);
  { dim3 g(993, 6); k_gemm<0><<<g, 256, 0, stream>>>(reg2, wqkvT, reg1, NPIX, 768); }
  k_conv<<<3969, 256, 0, stream>>>(reg1, w_dw, reg2);
  k_ln<<<31752, 256, 0, stream>>>(reg2, ln_g, ln_b, q_bias, v_bias, scale, reg1);
  k_attn<<<4096, 256, 0, stream>>>(reg1, biasT, reg2);
  { dim3 g(993, 2); k_gemm<1><<<g, 256, 0, stream>>>(reg2, wprojT, out, NPIX, 256); }
}

// Round 6
// 651.677 us; speedup vs baseline: 1.2424x; 1.0126x over previous
//
#include <hip/hip_runtime.h>

typedef unsigned short ushort;
typedef __bf16 bf16x8 __attribute__((ext_vector_type(8)));
typedef float f32x4 __attribute__((ext_vector_type(4)));
typedef float f4 __attribute__((ext_vector_type(4)));
typedef unsigned short us8 __attribute__((ext_vector_type(8)));
typedef unsigned short us4 __attribute__((ext_vector_type(4)));

#define NPIX 127008   // 8*126*126
#define HDIM 126
#define WDIM 126

__device__ __forceinline__ float bf2f(ushort u) {
  unsigned v = ((unsigned)u) << 16;
  return __builtin_bit_cast(float, v);
}
__device__ __forceinline__ ushort f2bf(float f) {
  unsigned x = __builtin_bit_cast(unsigned, f);
  x += 0x7fffu + ((x >> 16) & 1u);
  return (ushort)(x >> 16);
}

__global__ void k_cvt_wT(const float* __restrict__ in, ushort* __restrict__ out, int N, int K) {
  const int t = blockIdx.x * 256 + threadIdx.x;
  const int n = t / K, k = t - n * K;
  out[t] = f2bf(in[(size_t)k * N + n]);
}

// ---------------- CPB bias MLP ----------------
__device__ __forceinline__ float frel(int i) {
  const float v = (float)(i - 7) * (8.0f / 7.0f);
  const float a = log1pf(fabsf(v)) * 0.4808983469629878f; // 1/ln(8)
  return v < 0.f ? -a : a;
}

__global__ __launch_bounds__(256) void k_cpb1(const float* __restrict__ w0,
    const float* __restrict__ b0, const float* __restrict__ w1, float* __restrict__ tmp) {
  const int p = blockIdx.x * 4 + (threadIdx.x >> 6);
  const int lane = threadIdx.x & 63;
  if (p >= 225) return;
  const float r0 = frel(p / 15), r1 = frel(p % 15);
  float hv[8];
#pragma unroll
  for (int jj = 0; jj < 8; ++jj) {
    const int j = lane * 8 + jj;
    hv[jj] = fmaxf(0.f, r0 * w0[j] + r1 * w0[512 + j] + b0[j]);
  }
  for (int h = 0; h < 8; ++h) {
    float part = 0.f;
#pragma unroll
    for (int jj = 0; jj < 8; ++jj) part += hv[jj] * w1[(lane * 8 + jj) * 8 + h];
    for (int o = 32; o; o >>= 1) part += __shfl_xor(part, o);
    if (lane == 0) tmp[p * 8 + h] = 16.f / (1.f + __expf(-part));
  }
}

__global__ void k_cpb2(const float* __restrict__ tmp, float* __restrict__ biasT) {
  const int t = blockIdx.x * 256 + threadIdx.x; // 32768
  const int h = t >> 12, k = (t >> 6) & 63, q = t & 63;
  const int d0 = (q >> 3) - (k >> 3) + 7, d1 = (q & 7) - (k & 7) + 7;
  biasT[t] = tmp[(d0 * 15 + d1) * 8 + h];
}

// ---------------- bf16 MFMA GEMM: C[M,N] = A[M,K=256] * Bt[N,K]^T ----------------
// AF32=1: A is f32, converted to bf16 during register-staged LDS write
// (same LDS byte layout as global_load_lds: thread t writes bytes [t*16, t*16+16)).
#define GLL(g, l) __builtin_amdgcn_global_load_lds( \
    (const __attribute__((address_space(1))) void*)(g), \
    (__attribute__((address_space(3))) void*)(l), 16, 0, 0)

template <int OUTF, int AF32>
__global__ __launch_bounds__(256) void k_gemm(const void* __restrict__ Av,
                                              const ushort* __restrict__ Bt,
                                              void* __restrict__ Cv, int M, int N) {
  constexpr int K = 256;
  __shared__ ushort lsA[128 * 32];
  __shared__ ushort lsB[128 * 32];
  const int tid = threadIdx.x;
  const int wid = tid >> 6, lane = tid & 63;
  const int m0 = blockIdx.y * 128, n0 = blockIdx.x * 128;  // N-tiles fastest -> L3 A-reuse

  f32x4 acc[4][4];
#pragma unroll
  for (int i = 0; i < 4; ++i)
#pragma unroll
    for (int j = 0; j < 4; ++j) acc[i][j] = 0.f;

  const int srow = tid >> 2, sk = (tid & 3) * 8;
  const int aw = (wid >> 1) * 64, bw = (wid & 1) * 64;
  const int fr = lane & 15, kg = (lane >> 4) * 8;
  char* lA = (char*)lsA + wid * 1024;
  char* lB = (char*)lsB + wid * 1024;

  int ra0 = m0 + srow;      if (ra0 >= M) ra0 = M - 1;
  int ra1 = m0 + srow + 64; if (ra1 >= M) ra1 = M - 1;
  const int rb0 = n0 + srow, rb1 = n0 + srow + 64;

  const ushort* A16 = (const ushort*)Av;
  const float*  A32 = (const float*)Av;

  for (int kt = 0; kt < K; kt += 32) {
    __syncthreads();
    if constexpr (AF32) {
      const f4 a00 = *(const f4*)&A32[(size_t)ra0 * K + kt + sk];
      const f4 a01 = *(const f4*)&A32[(size_t)ra0 * K + kt + sk + 4];
      const f4 a10 = *(const f4*)&A32[(size_t)ra1 * K + kt + sk];
      const f4 a11 = *(const f4*)&A32[(size_t)ra1 * K + kt + sk + 4];
      us8 o0, o1;
#pragma unroll
      for (int j = 0; j < 4; ++j) {
        o0[j] = f2bf(a00[j]); o0[4 + j] = f2bf(a01[j]);
        o1[j] = f2bf(a10[j]); o1[4 + j] = f2bf(a11[j]);
      }
      *(us8*)&lsA[srow * 32 + sk] = o0;
      *(us8*)&lsA[(srow + 64) * 32 + sk] = o1;
    } else {
      GLL(A16 + (size_t)ra0 * K + kt + sk, lA);
      GLL(A16 + (size_t)ra1 * K + kt + sk, lA + 4096);
    }
    GLL(Bt + (size_t)rb0 * K + kt + sk, lB);
    GLL(Bt + (size_t)rb1 * K + kt + sk, lB + 4096);
    __syncthreads();
    bf16x8 af[4], bb[4];
#pragma unroll
    for (int i = 0; i < 4; ++i)
      af[i] = *(const bf16x8*)&lsA[(aw + i * 16 + fr) * 32 + kg];
#pragma unroll
    for (int j = 0; j < 4; ++j)
      bb[j] = *(const bf16x8*)&lsB[(bw + j * 16 + fr) * 32 + kg];
#pragma unroll
    for (int i = 0; i < 4; ++i)
#pragma unroll
      for (int j = 0; j < 4; ++j)
        acc[i][j] = __builtin_amdgcn_mfma_f32_16x16x32_bf16(af[i], bb[j], acc[i][j], 0, 0, 0);
  }

  const int r4 = (lane >> 4) * 4, cc = lane & 15;
#pragma unroll
  for (int i = 0; i < 4; ++i) {
#pragma unroll
    for (int j = 0; j < 4; ++j) {
      const int gc = n0 + bw + j * 16 + cc;
#pragma unroll
      for (int r = 0; r < 4; ++r) {
        const int gr = m0 + aw + i * 16 + r4 + r;
        if (gr < M) {
          if constexpr (OUTF == 0)
            ((ushort*)Cv)[(size_t)gr * N + gc] = f2bf(acc[i][j][r]);
          else
            ((float*)Cv)[(size_t)gr * N + gc] = acc[i][j][r];
        }
      }
    }
  }
}

// ------- fused 3x3 depthwise conv + LN + bias + l2n + logit-scale + window scatter -------
// wave per pixel; 4 px/block; XCD-chunked swizzle (31752 = 8 x 3969 = one image/XCD)
__global__ __launch_bounds__(256) void k_convln(const ushort* __restrict__ pre,
    const float* __restrict__ wdw,
    const float* __restrict__ gamma, const float* __restrict__ beta,
    const float* __restrict__ qb, const float* __restrict__ vb,
    const float* __restrict__ scale, ushort* __restrict__ qkvw) {
  const int orig = blockIdx.x;
  const int swz = (orig & 7) * 3969 + (orig >> 3);
  const int pix = swz * 4 + (threadIdx.x >> 6);
  const int lane = threadIdx.x & 63;
  const int w = pix % WDIM, t2 = pix / WDIM, h = t2 % HDIM, b = t2 / HDIM;

  // conv: 12 channels/lane at (lane + 64*c)*4, c in {0,1,2} (q,k,v 256-blocks)
  float y[3][4];
#pragma unroll
  for (int c = 0; c < 3; ++c)
#pragma unroll
    for (int j = 0; j < 4; ++j) y[c][j] = 0.f;

#pragma unroll
  for (int dy = 0; dy < 3; ++dy) {
    const int hh = h + dy - 1;
    if (hh < 0 || hh >= HDIM) continue;
#pragma unroll
    for (int dx = 0; dx < 3; ++dx) {
      const int ww2 = w + dx - 1;
      if (ww2 < 0 || ww2 >= WDIM) continue;
      const ushort* row = pre + ((size_t)((b * HDIM + hh) * WDIM + ww2)) * 768;
      const float* wrow = wdw + (dy * 3 + dx) * 768;
#pragma unroll
      for (int c = 0; c < 3; ++c) {
        const int chb = (lane + 64 * c) * 4;
        const us4 u = *(const us4*)&row[chb];
        const f4 wv = *(const f4*)&wrow[chb];
#pragma unroll
        for (int j = 0; j < 4; ++j) y[c][j] += bf2f(u[j]) * wv[j];
      }
    }
  }

  // LayerNorm over 768 channels (wave reduce)
  float s = 0.f;
#pragma unroll
  for (int c = 0; c < 3; ++c)
#pragma unroll
    for (int j = 0; j < 4; ++j) s += y[c][j];
  for (int o = 32; o; o >>= 1) s += __shfl_xor(s, o);
  const float mu = s * (1.f / 768.f);
  float ss = 0.f;
#pragma unroll
  for (int c = 0; c < 3; ++c)
#pragma unroll
    for (int j = 0; j < 4; ++j) { const float d = y[c][j] - mu; ss += d * d; }
  for (int o = 32; o; o >>= 1) ss += __shfl_xor(ss, o);
  const float rs = rsqrtf(ss * (1.f / 768.f) + 1e-5f);

#pragma unroll
  for (int c = 0; c < 3; ++c) {
    const int chb = (lane + 64 * c) * 4;
#pragma unroll
    for (int j = 0; j < 4; ++j)
      y[c][j] = (y[c][j] - mu) * rs * gamma[chb + j] + beta[chb + j];
  }
#pragma unroll
  for (int j = 0; j < 4; ++j) { y[0][j] += qb[lane * 4 + j]; y[2][j] += vb[lane * 4 + j]; }

  // l2norm per 32-ch head group (8 lanes x 4ch) for q and k
#pragma unroll
  for (int c = 0; c < 2; ++c) {
    float g = y[c][0] * y[c][0] + y[c][1] * y[c][1] + y[c][2] * y[c][2] + y[c][3] * y[c][3];
    g += __shfl_xor(g, 1); g += __shfl_xor(g, 2); g += __shfl_xor(g, 4);
    const float rn = rsqrtf(fmaxf(g, 1.55e-5f));
#pragma unroll
    for (int j = 0; j < 4; ++j) y[c][j] *= rn;
  }
  const float ls = __expf(fminf(scale[lane >> 3], 4.60517025f)); // min(scale, ln 100)
#pragma unroll
  for (int j = 0; j < 4; ++j) y[0][j] *= ls;

  // window scatter: hp=h+1, wp=w+1; win=(hp&15)*16+(wp&15); tok=(hp>>4)*8+(wp>>4)
  const int hp = h + 1, wp = w + 1;
  const int dstrow = (((b << 8) + ((hp & 15) << 4) + (wp & 15)) << 6) + ((hp >> 4) << 3) + (wp >> 4);
  ushort* orow = qkvw + (size_t)dstrow * 768;
#pragma unroll
  for (int c = 0; c < 3; ++c) {
    us4 u;
#pragma unroll
    for (int j = 0; j < 4; ++j) u[j] = f2bf(y[c][j]);
    *(us4*)&orow[(lane + 64 * c) * 4] = u;
  }
}

// ---------------- MFMA attention: 4 waves/block, 1 wave per (window, head) ----------------
__global__ __launch_bounds__(256) void k_attn(const ushort* __restrict__ qkvw,
    const float* __restrict__ biasT, ushort* __restrict__ aout) {
  __shared__ __align__(16) ushort Pq[4][64][72]; // P[q][key], stride 144B
  __shared__ __align__(16) ushort Vs[4][64][32]; // V[key][d]
  const int wid = threadIdx.x >> 6, lane = threadIdx.x & 63;
  const int u = blockIdx.x * 4 + wid;
  const int head = u >> 11, wl = u & 2047;
  const int b = wl >> 8, wh = (wl >> 4) & 15, ww = wl & 15;
  const int c = lane & 15, g = lane >> 4;
  const int g4 = g * 4, g8 = g * 8;
  const ushort* wb = qkvw + (size_t)wl * 64 * 768;
  const us8 zz = 0;

  const bool e_r0 = (wh == 0), e_r7 = (wh == 15), e_c0 = (ww == 0), e_c7 = (ww == 15);
#define TOKVALID(t) (!(((e_r0) & (((t) >> 3) == 0)) | ((e_r7) & (((t) >> 3) == 7)) | \
                       ((e_c0) & (((t) & 7) == 0)) | ((e_c7) & (((t) & 7) == 7))))

  // stage V: ALL 32 dims; zero invalid-token rows (their global rows are garbage)
  {
    const bool tv = TOKVALID(lane);
    const ushort* vp = wb + (size_t)lane * 768 + 512 + head * 32;
    us8 v0 = *(const us8*)vp;
    us8 v1 = *(const us8*)(vp + 8);
    us8 v2 = *(const us8*)(vp + 16);
    us8 v3 = *(const us8*)(vp + 24);
    v0 = tv ? v0 : zz;
    v1 = tv ? v1 : zz;
    v2 = tv ? v2 : zz;
    v3 = tv ? v3 : zz;
    *(us8*)&Vs[wid][lane][0]  = v0;
    *(us8*)&Vs[wid][lane][8]  = v1;
    *(us8*)&Vs[wid][lane][16] = v2;
    *(us8*)&Vs[wid][lane][24] = v3;
  }

  // QK^T (swapped): A = K fragments, B = Q fragments; zero invalid fragments
  bf16x8 kf[4], qf[4];
#pragma unroll
  for (int ki = 0; ki < 4; ++ki) {
    const int tk = ki * 16 + c;
    us8 kv = *(const us8*)&wb[(size_t)tk * 768 + 256 + head * 32 + g8];
    kv = TOKVALID(tk) ? kv : zz;
    kf[ki] = __builtin_bit_cast(bf16x8, kv);
  }
#pragma unroll
  for (int qj = 0; qj < 4; ++qj) {
    const int tq = qj * 16 + c;
    us8 qv = *(const us8*)&wb[(size_t)tq * 768 + head * 32 + g8];
    qv = TOKVALID(tq) ? qv : zz;
    qf[qj] = __builtin_bit_cast(bf16x8, qv);
  }

  f32x4 st[4][4];
#pragma unroll
  for (int ki = 0; ki < 4; ++ki)
#pragma unroll
    for (int qj = 0; qj < 4; ++qj)
      st[ki][qj] = __builtin_amdgcn_mfma_f32_16x16x32_bf16(kf[ki], qf[qj], f32x4{0.f,0.f,0.f,0.f}, 0, 0, 0);

  const float* bt = biasT + (head << 12);
#pragma unroll
  for (int qj = 0; qj < 4; ++qj) {
    const int q = qj * 16 + c;
    float s[16];
#pragma unroll
    for (int ki = 0; ki < 4; ++ki)
#pragma unroll
      for (int r = 0; r < 4; ++r) {
        const int key = ki * 16 + g4 + r;
        const float bias = bt[(key << 6) + q];
        s[ki * 4 + r] = TOKVALID(key) ? st[ki][qj][r] + bias : -1e30f;
      }
    float m = s[0];
#pragma unroll
    for (int i = 1; i < 16; ++i) m = fmaxf(m, s[i]);
    m = fmaxf(m, __shfl_xor(m, 16));
    m = fmaxf(m, __shfl_xor(m, 32));
    float den = 0.f;
#pragma unroll
    for (int i = 0; i < 16; ++i) { s[i] = __expf(s[i] - m); den += s[i]; }
    den += __shfl_xor(den, 16);
    den += __shfl_xor(den, 32);
    const float inv = 1.f / den;
#pragma unroll
    for (int ki = 0; ki < 4; ++ki) {
      us4 pk;
#pragma unroll
      for (int r = 0; r < 4; ++r) pk[r] = f2bf(s[ki * 4 + r] * inv);
      *(us4*)&Pq[wid][q][ki * 16 + g4] = pk;
    }
  }
  __syncthreads();

  // PV
  f32x4 ao[4][2];
#pragma unroll
  for (int qi = 0; qi < 4; ++qi)
#pragma unroll
    for (int di = 0; di < 2; ++di) ao[qi][di] = 0.f;
#pragma unroll
  for (int kc = 0; kc < 2; ++kc) {
    bf16x8 af[4];
#pragma unroll
    for (int qi = 0; qi < 4; ++qi)
      af[qi] = __builtin_bit_cast(bf16x8, *(const us8*)&Pq[wid][qi * 16 + c][kc * 32 + g8]);
#pragma unroll
    for (int di = 0; di < 2; ++di) {
      us8 bv;
#pragma unroll
      for (int j = 0; j < 8; ++j) bv[j] = Vs[wid][kc * 32 + g8 + j][di * 16 + c];
      const bf16x8 bb = __builtin_bit_cast(bf16x8, bv);
#pragma unroll
      for (int qi = 0; qi < 4; ++qi)
        ao[qi][di] = __builtin_amdgcn_mfma_f32_16x16x32_bf16(af[qi], bb, ao[qi][di], 0, 0, 0);
    }
  }

#pragma unroll
  for (int qi = 0; qi < 4; ++qi)
#pragma unroll
    for (int r = 0; r < 4; ++r) {
      const int q = qi * 16 + g4 + r;
      if (TOKVALID(q)) {
        const int h = (q >> 3) * 16 + wh - 1, w2 = (q & 7) * 16 + ww - 1;
        ushort* op = aout + ((size_t)((b * HDIM + h) * WDIM + w2)) * 256 + head * 32;
        op[c] = f2bf(ao[qi][0][r]);
        op[16 + c] = f2bf(ao[qi][1][r]);
      }
    }
#undef TOKVALID
}

// ---------------- launch ----------------
extern "C" void kernel_launch(void* const* d_in, const int* in_sizes, int n_in,
                              void* d_out, int out_size, void* d_ws, size_t ws_size,
                              hipStream_t stream) {
  (void)in_sizes; (void)n_in; (void)out_size; (void)ws_size;
  const float* x      = (const float*)d_in[0];
  const float* w_qkv  = (const float*)d_in[1];
  const float* w_dw   = (const float*)d_in[2];
  const float* ln_g   = (const float*)d_in[3];
  const float* ln_b   = (const float*)d_in[4];
  const float* q_bias = (const float*)d_in[5];
  const float* v_bias = (const float*)d_in[6];
  const float* scale  = (const float*)d_in[7];
  const float* cpb_w0 = (const float*)d_in[8];
  const float* cpb_b0 = (const float*)d_in[9];
  const float* cpb_w1 = (const float*)d_in[10];
  const float* w_proj = (const float*)d_in[11];
  float* out = (float*)d_out;

  char* ws = (char*)d_ws;
  const size_t PRE  = (size_t)NPIX * 768 * 2;     // qkv_pre; later reused for attn_out
  const size_t QKVW = (size_t)131072 * 768 * 2;   // window-padded qkv
  ushort* pre    = (ushort*)ws;
  ushort* qkvw   = (ushort*)(ws + PRE);
  ushort* aoutb  = pre;  // attn_out reuses pre (dead after convln)
  ushort* wqkvT  = (ushort*)(ws + PRE + QKVW);
  ushort* wprojT = (ushort*)(ws + PRE + QKVW + (size_t)768 * 256 * 2);
  float*  cpbtmp = (float*)(ws + PRE + QKVW + (size_t)768 * 256 * 2 + (size_t)256 * 256 * 2);
  float*  biasT  = (float*)(ws + PRE + QKVW + (size_t)768 * 256 * 2 + (size_t)256 * 256 * 2 + 8192);

  k_cvt_wT<<<768, 256, 0, stream>>>(w_qkv, wqkvT, 768, 256);
  k_cvt_wT<<<256, 256, 0, stream>>>(w_proj, wprojT, 256, 256);
  k_cpb1<<<57, 256, 0, stream>>>(cpb_w0, cpb_b0, cpb_w1, cpbtmp);
  k_cpb2<<<128, 256, 0, stream>>>(cpbtmp, biasT);
  { dim3 g(6, 993); k_gemm<0, 1><<<g, 256, 0, stream>>>(x, wqkvT, pre, NPIX, 768); }
  k_convln<<<31752, 256, 0, stream>>>(pre, w_dw, ln_g, ln_b, q_bias, v_bias, scale, qkvw);
  k_attn<<<4096, 256, 0, stream>>>(qkvw, biasT, aoutb);
  { dim3 g(2, 993); k_gemm<1, 0><<<g, 256, 0, stream>>>(aoutb, wprojT, out, NPIX, 256); }
}

// Round 7
// 558.051 us; speedup vs baseline: 1.4509x; 1.1678x over previous
//
#include <hip/hip_runtime.h>

typedef unsigned short ushort;
typedef __bf16 bf16x8 __attribute__((ext_vector_type(8)));
typedef float f32x4 __attribute__((ext_vector_type(4)));
typedef float f4 __attribute__((ext_vector_type(4)));
typedef unsigned short us8 __attribute__((ext_vector_type(8)));
typedef unsigned short us4 __attribute__((ext_vector_type(4)));

#define NPIX 127008   // 8*126*126
#define HDIM 126
#define WDIM 126

__device__ __forceinline__ float bf2f(ushort u) {
  unsigned v = ((unsigned)u) << 16;
  return __builtin_bit_cast(float, v);
}
__device__ __forceinline__ ushort f2bf(float f) {
  unsigned x = __builtin_bit_cast(unsigned, f);
  x += 0x7fffu + ((x >> 16) & 1u);
  return (ushort)(x >> 16);
}

__global__ void k_cvt_wT(const float* __restrict__ in, ushort* __restrict__ out, int N, int K) {
  const int t = blockIdx.x * 256 + threadIdx.x;
  const int n = t / K, k = t - n * K;
  out[t] = f2bf(in[(size_t)k * N + n]);
}

// ---------------- CPB bias MLP ----------------
__device__ __forceinline__ float frel(int i) {
  const float v = (float)(i - 7) * (8.0f / 7.0f);
  const float a = log1pf(fabsf(v)) * 0.4808983469629878f; // 1/ln(8)
  return v < 0.f ? -a : a;
}

__global__ __launch_bounds__(256) void k_cpb1(const float* __restrict__ w0,
    const float* __restrict__ b0, const float* __restrict__ w1, float* __restrict__ tmp) {
  const int p = blockIdx.x * 4 + (threadIdx.x >> 6);
  const int lane = threadIdx.x & 63;
  if (p >= 225) return;
  const float r0 = frel(p / 15), r1 = frel(p % 15);
  float hv[8];
#pragma unroll
  for (int jj = 0; jj < 8; ++jj) {
    const int j = lane * 8 + jj;
    hv[jj] = fmaxf(0.f, r0 * w0[j] + r1 * w0[512 + j] + b0[j]);
  }
  for (int h = 0; h < 8; ++h) {
    float part = 0.f;
#pragma unroll
    for (int jj = 0; jj < 8; ++jj) part += hv[jj] * w1[(lane * 8 + jj) * 8 + h];
    for (int o = 32; o; o >>= 1) part += __shfl_xor(part, o);
    if (lane == 0) tmp[p * 8 + h] = 16.f / (1.f + __expf(-part));
  }
}

__global__ void k_cpb2(const float* __restrict__ tmp, float* __restrict__ biasT) {
  const int t = blockIdx.x * 256 + threadIdx.x; // 32768
  const int h = t >> 12, k = (t >> 6) & 63, q = t & 63;
  const int d0 = (q >> 3) - (k >> 3) + 7, d1 = (q & 7) - (k & 7) + 7;
  biasT[t] = tmp[(d0 * 15 + d1) * 8 + h];
}

// ---------------- bf16 MFMA GEMM: C[M,N] = A[M,K=256] * Bt[N,K]^T ----------------
#define GLL(g, l) __builtin_amdgcn_global_load_lds( \
    (const __attribute__((address_space(1))) void*)(g), \
    (__attribute__((address_space(3))) void*)(l), 16, 0, 0)

template <int OUTF, int AF32>
__global__ __launch_bounds__(256) void k_gemm(const void* __restrict__ Av,
                                              const ushort* __restrict__ Bt,
                                              void* __restrict__ Cv, int M, int N) {
  constexpr int K = 256;
  __shared__ ushort lsA[128 * 32];
  __shared__ ushort lsB[128 * 32];
  const int tid = threadIdx.x;
  const int wid = tid >> 6, lane = tid & 63;
  const int m0 = blockIdx.y * 128, n0 = blockIdx.x * 128;  // N-tiles fastest -> L3 A-reuse

  f32x4 acc[4][4];
#pragma unroll
  for (int i = 0; i < 4; ++i)
#pragma unroll
    for (int j = 0; j < 4; ++j) acc[i][j] = 0.f;

  const int srow = tid >> 2, sk = (tid & 3) * 8;
  const int aw = (wid >> 1) * 64, bw = (wid & 1) * 64;
  const int fr = lane & 15, kg = (lane >> 4) * 8;
  char* lA = (char*)lsA + wid * 1024;
  char* lB = (char*)lsB + wid * 1024;

  int ra0 = m0 + srow;      if (ra0 >= M) ra0 = M - 1;
  int ra1 = m0 + srow + 64; if (ra1 >= M) ra1 = M - 1;
  const int rb0 = n0 + srow, rb1 = n0 + srow + 64;

  const ushort* A16 = (const ushort*)Av;
  const float*  A32 = (const float*)Av;

  for (int kt = 0; kt < K; kt += 32) {
    __syncthreads();
    if constexpr (AF32) {
      const f4 a00 = *(const f4*)&A32[(size_t)ra0 * K + kt + sk];
      const f4 a01 = *(const f4*)&A32[(size_t)ra0 * K + kt + sk + 4];
      const f4 a10 = *(const f4*)&A32[(size_t)ra1 * K + kt + sk];
      const f4 a11 = *(const f4*)&A32[(size_t)ra1 * K + kt + sk + 4];
      us8 o0, o1;
#pragma unroll
      for (int j = 0; j < 4; ++j) {
        o0[j] = f2bf(a00[j]); o0[4 + j] = f2bf(a01[j]);
        o1[j] = f2bf(a10[j]); o1[4 + j] = f2bf(a11[j]);
      }
      *(us8*)&lsA[srow * 32 + sk] = o0;
      *(us8*)&lsA[(srow + 64) * 32 + sk] = o1;
    } else {
      GLL(A16 + (size_t)ra0 * K + kt + sk, lA);
      GLL(A16 + (size_t)ra1 * K + kt + sk, lA + 4096);
    }
    GLL(Bt + (size_t)rb0 * K + kt + sk, lB);
    GLL(Bt + (size_t)rb1 * K + kt + sk, lB + 4096);
    __syncthreads();
    bf16x8 af[4], bb[4];
#pragma unroll
    for (int i = 0; i < 4; ++i)
      af[i] = *(const bf16x8*)&lsA[(aw + i * 16 + fr) * 32 + kg];
#pragma unroll
    for (int j = 0; j < 4; ++j)
      bb[j] = *(const bf16x8*)&lsB[(bw + j * 16 + fr) * 32 + kg];
#pragma unroll
    for (int i = 0; i < 4; ++i)
#pragma unroll
      for (int j = 0; j < 4; ++j)
        acc[i][j] = __builtin_amdgcn_mfma_f32_16x16x32_bf16(af[i], bb[j], acc[i][j], 0, 0, 0);
  }

  const int r4 = (lane >> 4) * 4, cc = lane & 15;
#pragma unroll
  for (int i = 0; i < 4; ++i) {
#pragma unroll
    for (int j = 0; j < 4; ++j) {
      const int gc = n0 + bw + j * 16 + cc;
#pragma unroll
      for (int r = 0; r < 4; ++r) {
        const int gr = m0 + aw + i * 16 + r4 + r;
        if (gr < M) {
          if constexpr (OUTF == 0)
            ((ushort*)Cv)[(size_t)gr * N + gc] = f2bf(acc[i][j][r]);
          else
            ((float*)Cv)[(size_t)gr * N + gc] = acc[i][j][r];
        }
      }
    }
  }
}

// ------- sliding-window 3x3 depthwise conv, output scattered to window layout -------
// thread = (row-half, 8-ch chunk); walks 63 pixels; weights in regs; input slides L/C/R.
__global__ __launch_bounds__(256) void k_convw(const ushort* __restrict__ pre,
    const float* __restrict__ wdw, ushort* __restrict__ qkvw) {
  const int t = blockIdx.x * 256 + threadIdx.x;   // 756 blocks * 256 = 193536 = 96*2016
  const int chunk = t % 96;
  const int rh = t / 96;                          // 0..2015
  const int rowid = rh >> 1, half = rh & 1;
  const int b = rowid / HDIM, h = rowid - b * HDIM;
  const int c0 = chunk * 8;

  // weights: 9 taps x 8 ch in registers; zero rows that fall outside the image
  float wt[9][8];
#pragma unroll
  for (int tap = 0; tap < 9; ++tap) {
    const f4 wa = *(const f4*)&wdw[tap * 768 + c0];
    const f4 wb = *(const f4*)&wdw[tap * 768 + c0 + 4];
#pragma unroll
    for (int j = 0; j < 4; ++j) { wt[tap][j] = wa[j]; wt[tap][4 + j] = wb[j]; }
  }
  if (h == 0) {
#pragma unroll
    for (int tap = 0; tap < 3; ++tap)
#pragma unroll
      for (int j = 0; j < 8; ++j) wt[tap][j] = 0.f;
  }
  if (h == HDIM - 1) {
#pragma unroll
    for (int tap = 6; tap < 9; ++tap)
#pragma unroll
      for (int j = 0; j < 8; ++j) wt[tap][j] = 0.f;
  }

  const int hm = h > 0 ? h - 1 : 0, hp2 = h < HDIM - 1 ? h + 1 : HDIM - 1;
  const ushort* r0 = pre + (size_t)((b * HDIM + hm) * WDIM) * 768 + c0;
  const ushort* r1 = pre + (size_t)((b * HDIM + h) * WDIM) * 768 + c0;
  const ushort* r2 = pre + (size_t)((b * HDIM + hp2) * WDIM) * 768 + c0;

  const int w0 = half * 63;
  // rotating column registers: c0_,c1_,c2_ each [3 rows][8 ch] f32
  float ca[3][8], cb[3][8], cc_[3][8];

#define LOADCOL(dst, w)                                                   \
  {                                                                       \
    us8 u0 = *(const us8*)&r0[(size_t)(w) * 768];                         \
    us8 u1 = *(const us8*)&r1[(size_t)(w) * 768];                         \
    us8 u2 = *(const us8*)&r2[(size_t)(w) * 768];                         \
    _Pragma("unroll") for (int j = 0; j < 8; ++j) {                       \
      dst[0][j] = bf2f(u0[j]); dst[1][j] = bf2f(u1[j]); dst[2][j] = bf2f(u2[j]); } \
  }
#define ZEROCOL(dst)                                                      \
  { _Pragma("unroll") for (int rr = 0; rr < 3; ++rr)                      \
    _Pragma("unroll") for (int j = 0; j < 8; ++j) dst[rr][j] = 0.f; }

  if (half) { LOADCOL(ca, w0 - 1) } else { ZEROCOL(ca) }
  LOADCOL(cb, w0)

  const int dstc = ((b << 8) + (((h + 1) & 15) << 4)) << 6;  // const part of dstrow
  const int dsth = ((h + 1) >> 4) << 3;

#define BODY(L, C, R, w)                                                  \
  {                                                                       \
    if ((w) + 1 < WDIM) { LOADCOL(R, (w) + 1) } else { ZEROCOL(R) }       \
    float acc[8];                                                         \
    _Pragma("unroll") for (int j = 0; j < 8; ++j)                         \
      acc[j] = L[0][j] * wt[0][j] + C[0][j] * wt[1][j] + R[0][j] * wt[2][j] \
             + L[1][j] * wt[3][j] + C[1][j] * wt[4][j] + R[1][j] * wt[5][j] \
             + L[2][j] * wt[6][j] + C[2][j] * wt[7][j] + R[2][j] * wt[8][j]; \
    const int wp = (w) + 1;                                               \
    const int dstrow = dstc + ((wp & 15) << 6) + dsth + (wp >> 4);        \
    us8 o;                                                                \
    _Pragma("unroll") for (int j = 0; j < 8; ++j) o[j] = f2bf(acc[j]);    \
    *(us8*)&qkvw[(size_t)dstrow * 768 + c0] = o;                          \
  }

#pragma unroll 1
  for (int w = w0; w < w0 + 63; w += 3) {
    BODY(ca, cb, cc_, w)
    BODY(cb, cc_, ca, w + 1)
    BODY(cc_, ca, cb, w + 2)
  }
#undef BODY
#undef LOADCOL
#undef ZEROCOL
}

// ------- in-place LN + bias + l2n + logit-scale on the scattered qkv rows -------
__global__ __launch_bounds__(256) void k_ln2(ushort* __restrict__ qkvw,
    const float* __restrict__ gamma, const float* __restrict__ beta,
    const float* __restrict__ qb, const float* __restrict__ vb,
    const float* __restrict__ scale) {
  const int pix = blockIdx.x * 4 + (threadIdx.x >> 6);
  const int lane = threadIdx.x & 63;
  const int w = pix % WDIM, t2 = pix / WDIM, h = t2 % HDIM, b = t2 / HDIM;
  const int hp = h + 1, wp = w + 1;
  const int dstrow = (((b << 8) + ((hp & 15) << 4) + (wp & 15)) << 6) + ((hp >> 4) << 3) + (wp >> 4);
  ushort* row = qkvw + (size_t)dstrow * 768;

  float v[3][4];
#pragma unroll
  for (int c = 0; c < 3; ++c) {
    const us4 u = *(const us4*)&row[(lane + 64 * c) * 4];
#pragma unroll
    for (int j = 0; j < 4; ++j) v[c][j] = bf2f(u[j]);
  }
  float s = 0.f;
#pragma unroll
  for (int c = 0; c < 3; ++c)
#pragma unroll
    for (int j = 0; j < 4; ++j) s += v[c][j];
  for (int o = 32; o; o >>= 1) s += __shfl_xor(s, o);
  const float mu = s * (1.f / 768.f);
  float ss = 0.f;
#pragma unroll
  for (int c = 0; c < 3; ++c)
#pragma unroll
    for (int j = 0; j < 4; ++j) { const float d = v[c][j] - mu; ss += d * d; }
  for (int o = 32; o; o >>= 1) ss += __shfl_xor(ss, o);
  const float rs = rsqrtf(ss * (1.f / 768.f) + 1e-5f);

  float y[3][4];
#pragma unroll
  for (int c = 0; c < 3; ++c) {
    const int chb = (lane + 64 * c) * 4;
#pragma unroll
    for (int j = 0; j < 4; ++j)
      y[c][j] = (v[c][j] - mu) * rs * gamma[chb + j] + beta[chb + j];
  }
#pragma unroll
  for (int j = 0; j < 4; ++j) { y[0][j] += qb[lane * 4 + j]; y[2][j] += vb[lane * 4 + j]; }

#pragma unroll
  for (int c = 0; c < 2; ++c) {
    float g = y[c][0] * y[c][0] + y[c][1] * y[c][1] + y[c][2] * y[c][2] + y[c][3] * y[c][3];
    g += __shfl_xor(g, 1); g += __shfl_xor(g, 2); g += __shfl_xor(g, 4);
    const float rn = rsqrtf(fmaxf(g, 1.55e-5f));
#pragma unroll
    for (int j = 0; j < 4; ++j) y[c][j] *= rn;
  }
  const float ls = __expf(fminf(scale[lane >> 3], 4.60517025f));
#pragma unroll
  for (int j = 0; j < 4; ++j) y[0][j] *= ls;

#pragma unroll
  for (int c = 0; c < 3; ++c) {
    us4 u;
#pragma unroll
    for (int j = 0; j < 4; ++j) u[j] = f2bf(y[c][j]);
    *(us4*)&row[(lane + 64 * c) * 4] = u;
  }
}

// ---------------- MFMA attention: 4 waves/block, 1 wave per (window, head) ----------------
__global__ __launch_bounds__(256) void k_attn(const ushort* __restrict__ qkvw,
    const float* __restrict__ biasT, ushort* __restrict__ aout) {
  __shared__ __align__(16) ushort Pq[4][64][72];
  __shared__ __align__(16) ushort Vs[4][64][32];
  const int wid = threadIdx.x >> 6, lane = threadIdx.x & 63;
  const int u = blockIdx.x * 4 + wid;
  const int head = u >> 11, wl = u & 2047;
  const int b = wl >> 8, wh = (wl >> 4) & 15, ww = wl & 15;
  const int c = lane & 15, g = lane >> 4;
  const int g4 = g * 4, g8 = g * 8;
  const ushort* wb = qkvw + (size_t)wl * 64 * 768;
  const us8 zz = 0;

  const bool e_r0 = (wh == 0), e_r7 = (wh == 15), e_c0 = (ww == 0), e_c7 = (ww == 15);
#define TOKVALID(t) (!(((e_r0) & (((t) >> 3) == 0)) | ((e_r7) & (((t) >> 3) == 7)) | \
                       ((e_c0) & (((t) & 7) == 0)) | ((e_c7) & (((t) & 7) == 7))))

  {
    const bool tv = TOKVALID(lane);
    const ushort* vp = wb + (size_t)lane * 768 + 512 + head * 32;
    us8 v0 = *(const us8*)vp;
    us8 v1 = *(const us8*)(vp + 8);
    us8 v2 = *(const us8*)(vp + 16);
    us8 v3 = *(const us8*)(vp + 24);
    v0 = tv ? v0 : zz;
    v1 = tv ? v1 : zz;
    v2 = tv ? v2 : zz;
    v3 = tv ? v3 : zz;
    *(us8*)&Vs[wid][lane][0]  = v0;
    *(us8*)&Vs[wid][lane][8]  = v1;
    *(us8*)&Vs[wid][lane][16] = v2;
    *(us8*)&Vs[wid][lane][24] = v3;
  }

  bf16x8 kf[4], qf[4];
#pragma unroll
  for (int ki = 0; ki < 4; ++ki) {
    const int tk = ki * 16 + c;
    us8 kv = *(const us8*)&wb[(size_t)tk * 768 + 256 + head * 32 + g8];
    kv = TOKVALID(tk) ? kv : zz;
    kf[ki] = __builtin_bit_cast(bf16x8, kv);
  }
#pragma unroll
  for (int qj = 0; qj < 4; ++qj) {
    const int tq = qj * 16 + c;
    us8 qv = *(const us8*)&wb[(size_t)tq * 768 + head * 32 + g8];
    qv = TOKVALID(tq) ? qv : zz;
    qf[qj] = __builtin_bit_cast(bf16x8, qv);
  }

  f32x4 st[4][4];
#pragma unroll
  for (int ki = 0; ki < 4; ++ki)
#pragma unroll
    for (int qj = 0; qj < 4; ++qj)
      st[ki][qj] = __builtin_amdgcn_mfma_f32_16x16x32_bf16(kf[ki], qf[qj], f32x4{0.f,0.f,0.f,0.f}, 0, 0, 0);

  const float* bt = biasT + (head << 12);
#pragma unroll
  for (int qj = 0; qj < 4; ++qj) {
    const int q = qj * 16 + c;
    float s[16];
#pragma unroll
    for (int ki = 0; ki < 4; ++ki)
#pragma unroll
      for (int r = 0; r < 4; ++r) {
        const int key = ki * 16 + g4 + r;
        const float bias = bt[(key << 6) + q];
        s[ki * 4 + r] = TOKVALID(key) ? st[ki][qj][r] + bias : -1e30f;
      }
    float m = s[0];
#pragma unroll
    for (int i = 1; i < 16; ++i) m = fmaxf(m, s[i]);
    m = fmaxf(m, __shfl_xor(m, 16));
    m = fmaxf(m, __shfl_xor(m, 32));
    float den = 0.f;
#pragma unroll
    for (int i = 0; i < 16; ++i) { s[i] = __expf(s[i] - m); den += s[i]; }
    den += __shfl_xor(den, 16);
    den += __shfl_xor(den, 32);
    const float inv = 1.f / den;
#pragma unroll
    for (int ki = 0; ki < 4; ++ki) {
      us4 pk;
#pragma unroll
      for (int r = 0; r < 4; ++r) pk[r] = f2bf(s[ki * 4 + r] * inv);
      *(us4*)&Pq[wid][q][ki * 16 + g4] = pk;
    }
  }
  __syncthreads();

  f32x4 ao[4][2];
#pragma unroll
  for (int qi = 0; qi < 4; ++qi)
#pragma unroll
    for (int di = 0; di < 2; ++di) ao[qi][di] = 0.f;
#pragma unroll
  for (int kc = 0; kc < 2; ++kc) {
    bf16x8 af[4];
#pragma unroll
    for (int qi = 0; qi < 4; ++qi)
      af[qi] = __builtin_bit_cast(bf16x8, *(const us8*)&Pq[wid][qi * 16 + c][kc * 32 + g8]);
#pragma unroll
    for (int di = 0; di < 2; ++di) {
      us8 bv;
#pragma unroll
      for (int j = 0; j < 8; ++j) bv[j] = Vs[wid][kc * 32 + g8 + j][di * 16 + c];
      const bf16x8 bb = __builtin_bit_cast(bf16x8, bv);
#pragma unroll
      for (int qi = 0; qi < 4; ++qi)
        ao[qi][di] = __builtin_amdgcn_mfma_f32_16x16x32_bf16(af[qi], bb, ao[qi][di], 0, 0, 0);
    }
  }

#pragma unroll
  for (int qi = 0; qi < 4; ++qi)
#pragma unroll
    for (int r = 0; r < 4; ++r) {
      const int q = qi * 16 + g4 + r;
      if (TOKVALID(q)) {
        const int h = (q >> 3) * 16 + wh - 1, w2 = (q & 7) * 16 + ww - 1;
        ushort* op = aout + ((size_t)((b * HDIM + h) * WDIM + w2)) * 256 + head * 32;
        op[c] = f2bf(ao[qi][0][r]);
        op[16 + c] = f2bf(ao[qi][1][r]);
      }
    }
#undef TOKVALID
}

// ---------------- launch ----------------
extern "C" void kernel_launch(void* const* d_in, const int* in_sizes, int n_in,
                              void* d_out, int out_size, void* d_ws, size_t ws_size,
                              hipStream_t stream) {
  (void)in_sizes; (void)n_in; (void)out_size; (void)ws_size;
  const float* x      = (const float*)d_in[0];
  const float* w_qkv  = (const float*)d_in[1];
  const float* w_dw   = (const float*)d_in[2];
  const float* ln_g   = (const float*)d_in[3];
  const float* ln_b   = (const float*)d_in[4];
  const float* q_bias = (const float*)d_in[5];
  const float* v_bias = (const float*)d_in[6];
  const float* scale  = (const float*)d_in[7];
  const float* cpb_w0 = (const float*)d_in[8];
  const float* cpb_b0 = (const float*)d_in[9];
  const float* cpb_w1 = (const float*)d_in[10];
  const float* w_proj = (const float*)d_in[11];
  float* out = (float*)d_out;

  char* ws = (char*)d_ws;
  const size_t PRE  = (size_t)NPIX * 768 * 2;     // qkv_pre; reused for attn_out
  const size_t QKVW = (size_t)131072 * 768 * 2;   // window-padded qkv
  ushort* pre    = (ushort*)ws;
  ushort* qkvw   = (ushort*)(ws + PRE);
  ushort* aoutb  = pre;
  ushort* wqkvT  = (ushort*)(ws + PRE + QKVW);
  ushort* wprojT = (ushort*)(ws + PRE + QKVW + (size_t)768 * 256 * 2);
  float*  cpbtmp = (float*)(ws + PRE + QKVW + (size_t)768 * 256 * 2 + (size_t)256 * 256 * 2);
  float*  biasT  = (float*)(ws + PRE + QKVW + (size_t)768 * 256 * 2 + (size_t)256 * 256 * 2 + 8192);

  k_cvt_wT<<<768, 256, 0, stream>>>(w_qkv, wqkvT, 768, 256);
  k_cvt_wT<<<256, 256, 0, stream>>>(w_proj, wprojT, 256, 256);
  k_cpb1<<<57, 256, 0, stream>>>(cpb_w0, cpb_b0, cpb_w1, cpbtmp);
  k_cpb2<<<128, 256, 0, stream>>>(cpbtmp, biasT);
  { dim3 g(6, 993); k_gemm<0, 1><<<g, 256, 0, stream>>>(x, wqkvT, pre, NPIX, 768); }
  k_convw<<<756, 256, 0, stream>>>(pre, w_dw, qkvw);
  k_ln2<<<31752, 256, 0, stream>>>(qkvw, ln_g, ln_b, q_bias, v_bias, scale);
  k_attn<<<4096, 256, 0, stream>>>(qkvw, biasT, aoutb);
  { dim3 g(2, 993); k_gemm<1, 0><<<g, 256, 0, stream>>>(aoutb, wprojT, out, NPIX, 256); }
}

// Round 8
// 530.172 us; speedup vs baseline: 1.5272x; 1.0526x over previous
//
#include <hip/hip_runtime.h>

typedef unsigned short ushort;
typedef __bf16 bf16x8 __attribute__((ext_vector_type(8)));
typedef float f32x4 __attribute__((ext_vector_type(4)));
typedef float f4 __attribute__((ext_vector_type(4)));
typedef unsigned short us8 __attribute__((ext_vector_type(8)));
typedef unsigned short us4 __attribute__((ext_vector_type(4)));

#define NPIX 127008   // 8*126*126
#define HDIM 126
#define WDIM 126

__device__ __forceinline__ float bf2f(ushort u) {
  unsigned v = ((unsigned)u) << 16;
  return __builtin_bit_cast(float, v);
}
__device__ __forceinline__ ushort f2bf(float f) {
  unsigned x = __builtin_bit_cast(unsigned, f);
  x += 0x7fffu + ((x >> 16) & 1u);
  return (ushort)(x >> 16);
}

// ---------------- converts ----------------
__global__ void k_cvt_x(const float* __restrict__ x, ushort* __restrict__ xb, int n8) {
  const int stride = gridDim.x * blockDim.x;
  for (int i = blockIdx.x * blockDim.x + threadIdx.x; i < n8; i += stride) {
    const f4 a = *(const f4*)&x[(size_t)i * 8];
    const f4 b = *(const f4*)&x[(size_t)i * 8 + 4];
    us8 o;
#pragma unroll
    for (int j = 0; j < 4; ++j) { o[j] = f2bf(a[j]); o[4 + j] = f2bf(b[j]); }
    *(us8*)&xb[(size_t)i * 8] = o;
  }
}

__global__ void k_cvt_wT(const float* __restrict__ in, ushort* __restrict__ out, int N, int K) {
  const int t = blockIdx.x * 256 + threadIdx.x;
  const int n = t / K, k = t - n * K;
  out[t] = f2bf(in[(size_t)k * N + n]);
}

// ---------------- CPB bias MLP ----------------
__device__ __forceinline__ float frel(int i) {
  const float v = (float)(i - 7) * (8.0f / 7.0f);
  const float a = log1pf(fabsf(v)) * 0.4808983469629878f; // 1/ln(8)
  return v < 0.f ? -a : a;
}

__global__ __launch_bounds__(256) void k_cpb1(const float* __restrict__ w0,
    const float* __restrict__ b0, const float* __restrict__ w1, float* __restrict__ tmp) {
  const int p = blockIdx.x * 4 + (threadIdx.x >> 6);
  const int lane = threadIdx.x & 63;
  if (p >= 225) return;
  const float r0 = frel(p / 15), r1 = frel(p % 15);
  float hv[8];
#pragma unroll
  for (int jj = 0; jj < 8; ++jj) {
    const int j = lane * 8 + jj;
    hv[jj] = fmaxf(0.f, r0 * w0[j] + r1 * w0[512 + j] + b0[j]);
  }
  for (int h = 0; h < 8; ++h) {
    float part = 0.f;
#pragma unroll
    for (int jj = 0; jj < 8; ++jj) part += hv[jj] * w1[(lane * 8 + jj) * 8 + h];
    for (int o = 32; o; o >>= 1) part += __shfl_xor(part, o);
    if (lane == 0) tmp[p * 8 + h] = 16.f / (1.f + __expf(-part));
  }
}

__global__ void k_cpb2(const float* __restrict__ tmp, float* __restrict__ biasT) {
  const int t = blockIdx.x * 256 + threadIdx.x; // 32768
  const int h = t >> 12, k = (t >> 6) & 63, q = t & 63;
  const int d0 = (q >> 3) - (k >> 3) + 7, d1 = (q & 7) - (k & 7) + 7;
  biasT[t] = tmp[(d0 * 15 + d1) * 8 + h];
}

// ---------------- bf16 MFMA GEMM: C[M,N] = A[M,K=256] * Bt[N,K]^T ----------------
// 1D grid with bijective XCD-chunk swizzle (m204): each XCD owns a contiguous
// run of linear tile ids; NX n-tiles consecutive -> A panel L2-reused x NX,
// B (<=0.4MB) fully L2-resident per XCD.
#define GLL(g, l) __builtin_amdgcn_global_load_lds( \
    (const __attribute__((address_space(1))) void*)(g), \
    (__attribute__((address_space(3))) void*)(l), 16, 0, 0)

template <int OUTF, int NX>
__global__ __launch_bounds__(256) void k_gemm(const ushort* __restrict__ A,
                                              const ushort* __restrict__ Bt,
                                              void* __restrict__ Cv, int M, int N) {
  constexpr int K = 256;
  __shared__ ushort lsA[128 * 32];
  __shared__ ushort lsB[128 * 32];
  const int tid = threadIdx.x;
  const int wid = tid >> 6, lane = tid & 63;

  const int nwg = gridDim.x;
  const int q8 = nwg >> 3, r8 = nwg & 7;
  const int xcd = blockIdx.x & 7, pos = blockIdx.x >> 3;
  const int lin = (xcd < r8) ? xcd * (q8 + 1) + pos
                             : r8 * (q8 + 1) + (xcd - r8) * q8 + pos;
  const int m0 = (lin / NX) * 128, n0 = (lin % NX) * 128;

  f32x4 acc[4][4];
#pragma unroll
  for (int i = 0; i < 4; ++i)
#pragma unroll
    for (int j = 0; j < 4; ++j) acc[i][j] = 0.f;

  const int srow = tid >> 2, sk = (tid & 3) * 8;
  const int aw = (wid >> 1) * 64, bw = (wid & 1) * 64;
  const int fr = lane & 15, kg = (lane >> 4) * 8;
  char* lA = (char*)lsA + wid * 1024;
  char* lB = (char*)lsB + wid * 1024;

  int ra0 = m0 + srow;      if (ra0 >= M) ra0 = M - 1;
  int ra1 = m0 + srow + 64; if (ra1 >= M) ra1 = M - 1;
  const int rb0 = n0 + srow, rb1 = n0 + srow + 64;

  for (int kt = 0; kt < K; kt += 32) {
    __syncthreads();
    GLL(A + (size_t)ra0 * K + kt + sk, lA);
    GLL(A + (size_t)ra1 * K + kt + sk, lA + 4096);
    GLL(Bt + (size_t)rb0 * K + kt + sk, lB);
    GLL(Bt + (size_t)rb1 * K + kt + sk, lB + 4096);
    __syncthreads();
    bf16x8 af[4], bb[4];
#pragma unroll
    for (int i = 0; i < 4; ++i)
      af[i] = *(const bf16x8*)&lsA[(aw + i * 16 + fr) * 32 + kg];
#pragma unroll
    for (int j = 0; j < 4; ++j)
      bb[j] = *(const bf16x8*)&lsB[(bw + j * 16 + fr) * 32 + kg];
#pragma unroll
    for (int i = 0; i < 4; ++i)
#pragma unroll
      for (int j = 0; j < 4; ++j)
        acc[i][j] = __builtin_amdgcn_mfma_f32_16x16x32_bf16(af[i], bb[j], acc[i][j], 0, 0, 0);
  }

  const int r4 = (lane >> 4) * 4, cc = lane & 15;
#pragma unroll
  for (int i = 0; i < 4; ++i) {
#pragma unroll
    for (int j = 0; j < 4; ++j) {
      const int gc = n0 + bw + j * 16 + cc;
#pragma unroll
      for (int r = 0; r < 4; ++r) {
        const int gr = m0 + aw + i * 16 + r4 + r;
        if (gr < M) {
          if constexpr (OUTF == 0)
            ((ushort*)Cv)[(size_t)gr * N + gc] = f2bf(acc[i][j][r]);
          else
            ((float*)Cv)[(size_t)gr * N + gc] = acc[i][j][r];
        }
      }
    }
  }
}

// ------- sliding-window 3x3 depthwise conv, output scattered to window layout -------
// thread = (row, 21-px segment, 4-ch chunk); weights in regs; input slides L/C/R.
// 4-ch (not 8) keeps VGPR ~110 -> ~4 waves/SIMD; 6 segments/row -> 18k waves.
__global__ __launch_bounds__(256) void k_convw(const ushort* __restrict__ pre,
    const float* __restrict__ wdw, ushort* __restrict__ qkvw) {
  // 4536 blocks; bijective XCD swizzle (4536 = 8*567) for 3-row L2 reuse
  const int lin = (blockIdx.x & 7) * 567 + (blockIdx.x >> 3);
  const int t = lin * 256 + threadIdx.x;          // 1161216 = 192ch * 1008rows * 6seg
  const int chunk = t % 192;
  const int rs = t / 192;                         // 0..6047
  const int rowid = rs % 1008;                    // rowid fastest: rows h,h+-1 adjacent
  const int seg = rs / 1008;
  const int b = rowid / HDIM, h = rowid - b * HDIM;
  const int c0 = chunk * 4;

  float wt[9][4];
#pragma unroll
  for (int tap = 0; tap < 9; ++tap) {
    const f4 wa = *(const f4*)&wdw[tap * 768 + c0];
#pragma unroll
    for (int j = 0; j < 4; ++j) wt[tap][j] = wa[j];
  }
  if (h == 0) {
#pragma unroll
    for (int tap = 0; tap < 3; ++tap)
#pragma unroll
      for (int j = 0; j < 4; ++j) wt[tap][j] = 0.f;
  }
  if (h == HDIM - 1) {
#pragma unroll
    for (int tap = 6; tap < 9; ++tap)
#pragma unroll
      for (int j = 0; j < 4; ++j) wt[tap][j] = 0.f;
  }

  const int hm = h > 0 ? h - 1 : 0, hp2 = h < HDIM - 1 ? h + 1 : HDIM - 1;
  const ushort* r0 = pre + (size_t)((b * HDIM + hm) * WDIM) * 768 + c0;
  const ushort* r1 = pre + (size_t)((b * HDIM + h) * WDIM) * 768 + c0;
  const ushort* r2 = pre + (size_t)((b * HDIM + hp2) * WDIM) * 768 + c0;

  const int w0 = seg * 21;
  float ca[3][4], cb[3][4], cc_[3][4];

#define LOADCOL(dst, w)                                                   \
  {                                                                       \
    us4 u0 = *(const us4*)&r0[(size_t)(w) * 768];                         \
    us4 u1 = *(const us4*)&r1[(size_t)(w) * 768];                         \
    us4 u2 = *(const us4*)&r2[(size_t)(w) * 768];                         \
    _Pragma("unroll") for (int j = 0; j < 4; ++j) {                       \
      dst[0][j] = bf2f(u0[j]); dst[1][j] = bf2f(u1[j]); dst[2][j] = bf2f(u2[j]); } \
  }
#define ZEROCOL(dst)                                                      \
  { _Pragma("unroll") for (int rr = 0; rr < 3; ++rr)                      \
    _Pragma("unroll") for (int j = 0; j < 4; ++j) dst[rr][j] = 0.f; }

  if (w0 > 0) { LOADCOL(ca, w0 - 1) } else { ZEROCOL(ca) }
  LOADCOL(cb, w0)

  const int dstc = ((b << 8) + (((h + 1) & 15) << 4)) << 6;  // const part of dstrow
  const int dsth = ((h + 1) >> 4) << 3;

#define BODY(L, C, R, w)                                                  \
  {                                                                       \
    if ((w) + 1 < WDIM) { LOADCOL(R, (w) + 1) } else { ZEROCOL(R) }       \
    float acc[4];                                                         \
    _Pragma("unroll") for (int j = 0; j < 4; ++j)                         \
      acc[j] = L[0][j] * wt[0][j] + C[0][j] * wt[1][j] + R[0][j] * wt[2][j] \
             + L[1][j] * wt[3][j] + C[1][j] * wt[4][j] + R[1][j] * wt[5][j] \
             + L[2][j] * wt[6][j] + C[2][j] * wt[7][j] + R[2][j] * wt[8][j]; \
    const int wp = (w) + 1;                                               \
    const int dstrow = dstc + ((wp & 15) << 6) + dsth + (wp >> 4);        \
    us4 o;                                                                \
    _Pragma("unroll") for (int j = 0; j < 4; ++j) o[j] = f2bf(acc[j]);    \
    *(us4*)&qkvw[(size_t)dstrow * 768 + c0] = o;                          \
  }

#pragma unroll 1
  for (int w = w0; w < w0 + 21; w += 3) {
    BODY(ca, cb, cc_, w)
    BODY(cb, cc_, ca, w + 1)
    BODY(cc_, ca, cb, w + 2)
  }
#undef BODY
#undef LOADCOL
#undef ZEROCOL
}

// ------- in-place LN + bias + l2n + logit-scale on the scattered qkv rows -------
__global__ __launch_bounds__(256) void k_ln2(ushort* __restrict__ qkvw,
    const float* __restrict__ gamma, const float* __restrict__ beta,
    const float* __restrict__ qb, const float* __restrict__ vb,
    const float* __restrict__ scale) {
  const int pix = blockIdx.x * 4 + (threadIdx.x >> 6);
  const int lane = threadIdx.x & 63;
  const int w = pix % WDIM, t2 = pix / WDIM, h = t2 % HDIM, b = t2 / HDIM;
  const int hp = h + 1, wp = w + 1;
  const int dstrow = (((b << 8) + ((hp & 15) << 4) + (wp & 15)) << 6) + ((hp >> 4) << 3) + (wp >> 4);
  ushort* row = qkvw + (size_t)dstrow * 768;

  float v[3][4];
#pragma unroll
  for (int c = 0; c < 3; ++c) {
    const us4 u = *(const us4*)&row[(lane + 64 * c) * 4];
#pragma unroll
    for (int j = 0; j < 4; ++j) v[c][j] = bf2f(u[j]);
  }
  float s = 0.f;
#pragma unroll
  for (int c = 0; c < 3; ++c)
#pragma unroll
    for (int j = 0; j < 4; ++j) s += v[c][j];
  for (int o = 32; o; o >>= 1) s += __shfl_xor(s, o);
  const float mu = s * (1.f / 768.f);
  float ss = 0.f;
#pragma unroll
  for (int c = 0; c < 3; ++c)
#pragma unroll
    for (int j = 0; j < 4; ++j) { const float d = v[c][j] - mu; ss += d * d; }
  for (int o = 32; o; o >>= 1) ss += __shfl_xor(ss, o);
  const float rs = rsqrtf(ss * (1.f / 768.f) + 1e-5f);

  float y[3][4];
#pragma unroll
  for (int c = 0; c < 3; ++c) {
    const int chb = (lane + 64 * c) * 4;
#pragma unroll
    for (int j = 0; j < 4; ++j)
      y[c][j] = (v[c][j] - mu) * rs * gamma[chb + j] + beta[chb + j];
  }
#pragma unroll
  for (int j = 0; j < 4; ++j) { y[0][j] += qb[lane * 4 + j]; y[2][j] += vb[lane * 4 + j]; }

#pragma unroll
  for (int c = 0; c < 2; ++c) {
    float g = y[c][0] * y[c][0] + y[c][1] * y[c][1] + y[c][2] * y[c][2] + y[c][3] * y[c][3];
    g += __shfl_xor(g, 1); g += __shfl_xor(g, 2); g += __shfl_xor(g, 4);
    const float rn = rsqrtf(fmaxf(g, 1.55e-5f));
#pragma unroll
    for (int j = 0; j < 4; ++j) y[c][j] *= rn;
  }
  const float ls = __expf(fminf(scale[lane >> 3], 4.60517025f));
#pragma unroll
  for (int j = 0; j < 4; ++j) y[0][j] *= ls;

#pragma unroll
  for (int c = 0; c < 3; ++c) {
    us4 u;
#pragma unroll
    for (int j = 0; j < 4; ++j) u[j] = f2bf(y[c][j]);
    *(us4*)&row[(lane + 64 * c) * 4] = u;
  }
}

// ---------------- MFMA attention: 4 waves/block, 1 wave per (window, head) ----------------
__global__ __launch_bounds__(256) void k_attn(const ushort* __restrict__ qkvw,
    const float* __restrict__ biasT, ushort* __restrict__ aout) {
  __shared__ __align__(16) ushort Pq[4][64][72];
  __shared__ __align__(16) ushort Vs[4][64][32];
  const int wid = threadIdx.x >> 6, lane = threadIdx.x & 63;
  const int u = blockIdx.x * 4 + wid;
  const int head = u >> 11, wl = u & 2047;
  const int b = wl >> 8, wh = (wl >> 4) & 15, ww = wl & 15;
  const int c = lane & 15, g = lane >> 4;
  const int g4 = g * 4, g8 = g * 8;
  const ushort* wb = qkvw + (size_t)wl * 64 * 768;
  const us8 zz = 0;

  const bool e_r0 = (wh == 0), e_r7 = (wh == 15), e_c0 = (ww == 0), e_c7 = (ww == 15);
#define TOKVALID(t) (!(((e_r0) & (((t) >> 3) == 0)) | ((e_r7) & (((t) >> 3) == 7)) | \
                       ((e_c0) & (((t) & 7) == 0)) | ((e_c7) & (((t) & 7) == 7))))

  {
    const bool tv = TOKVALID(lane);
    const ushort* vp = wb + (size_t)lane * 768 + 512 + head * 32;
    us8 v0 = *(const us8*)vp;
    us8 v1 = *(const us8*)(vp + 8);
    us8 v2 = *(const us8*)(vp + 16);
    us8 v3 = *(const us8*)(vp + 24);
    v0 = tv ? v0 : zz;
    v1 = tv ? v1 : zz;
    v2 = tv ? v2 : zz;
    v3 = tv ? v3 : zz;
    *(us8*)&Vs[wid][lane][0]  = v0;
    *(us8*)&Vs[wid][lane][8]  = v1;
    *(us8*)&Vs[wid][lane][16] = v2;
    *(us8*)&Vs[wid][lane][24] = v3;
  }

  bf16x8 kf[4], qf[4];
#pragma unroll
  for (int ki = 0; ki < 4; ++ki) {
    const int tk = ki * 16 + c;
    us8 kv = *(const us8*)&wb[(size_t)tk * 768 + 256 + head * 32 + g8];
    kv = TOKVALID(tk) ? kv : zz;
    kf[ki] = __builtin_bit_cast(bf16x8, kv);
  }
#pragma unroll
  for (int qj = 0; qj < 4; ++qj) {
    const int tq = qj * 16 + c;
    us8 qv = *(const us8*)&wb[(size_t)tq * 768 + head * 32 + g8];
    qv = TOKVALID(tq) ? qv : zz;
    qf[qj] = __builtin_bit_cast(bf16x8, qv);
  }

  f32x4 st[4][4];
#pragma unroll
  for (int ki = 0; ki < 4; ++ki)
#pragma unroll
    for (int qj = 0; qj < 4; ++qj)
      st[ki][qj] = __builtin_amdgcn_mfma_f32_16x16x32_bf16(kf[ki], qf[qj], f32x4{0.f,0.f,0.f,0.f}, 0, 0, 0);

  const float* bt = biasT + (head << 12);
#pragma unroll
  for (int qj = 0; qj < 4; ++qj) {
    const int q = qj * 16 + c;
    float s[16];
#pragma unroll
    for (int ki = 0; ki < 4; ++ki)
#pragma unroll
      for (int r = 0; r < 4; ++r) {
        const int key = ki * 16 + g4 + r;
        const float bias = bt[(key << 6) + q];
        s[ki * 4 + r] = TOKVALID(key) ? st[ki][qj][r] + bias : -1e30f;
      }
    float m = s[0];
#pragma unroll
    for (int i = 1; i < 16; ++i) m = fmaxf(m, s[i]);
    m = fmaxf(m, __shfl_xor(m, 16));
    m = fmaxf(m, __shfl_xor(m, 32));
    float den = 0.f;
#pragma unroll
    for (int i = 0; i < 16; ++i) { s[i] = __expf(s[i] - m); den += s[i]; }
    den += __shfl_xor(den, 16);
    den += __shfl_xor(den, 32);
    const float inv = 1.f / den;
#pragma unroll
    for (int ki = 0; ki < 4; ++ki) {
      us4 pk;
#pragma unroll
      for (int r = 0; r < 4; ++r) pk[r] = f2bf(s[ki * 4 + r] * inv);
      *(us4*)&Pq[wid][q][ki * 16 + g4] = pk;
    }
  }
  __syncthreads();

  f32x4 ao[4][2];
#pragma unroll
  for (int qi = 0; qi < 4; ++qi)
#pragma unroll
    for (int di = 0; di < 2; ++di) ao[qi][di] = 0.f;
#pragma unroll
  for (int kc = 0; kc < 2; ++kc) {
    bf16x8 af[4];
#pragma unroll
    for (int qi = 0; qi < 4; ++qi)
      af[qi] = __builtin_bit_cast(bf16x8, *(const us8*)&Pq[wid][qi * 16 + c][kc * 32 + g8]);
#pragma unroll
    for (int di = 0; di < 2; ++di) {
      us8 bv;
#pragma unroll
      for (int j = 0; j < 8; ++j) bv[j] = Vs[wid][kc * 32 + g8 + j][di * 16 + c];
      const bf16x8 bb = __builtin_bit_cast(bf16x8, bv);
#pragma unroll
      for (int qi = 0; qi < 4; ++qi)
        ao[qi][di] = __builtin_amdgcn_mfma_f32_16x16x32_bf16(af[qi], bb, ao[qi][di], 0, 0, 0);
    }
  }

#pragma unroll
  for (int qi = 0; qi < 4; ++qi)
#pragma unroll
    for (int r = 0; r < 4; ++r) {
      const int q = qi * 16 + g4 + r;
      if (TOKVALID(q)) {
        const int h = (q >> 3) * 16 + wh - 1, w2 = (q & 7) * 16 + ww - 1;
        ushort* op = aout + ((size_t)((b * HDIM + h) * WDIM + w2)) * 256 + head * 32;
        op[c] = f2bf(ao[qi][0][r]);
        op[16 + c] = f2bf(ao[qi][1][r]);
      }
    }
#undef TOKVALID
}

// ---------------- launch ----------------
extern "C" void kernel_launch(void* const* d_in, const int* in_sizes, int n_in,
                              void* d_out, int out_size, void* d_ws, size_t ws_size,
                              hipStream_t stream) {
  (void)in_sizes; (void)n_in; (void)out_size; (void)ws_size;
  const float* x      = (const float*)d_in[0];
  const float* w_qkv  = (const float*)d_in[1];
  const float* w_dw   = (const float*)d_in[2];
  const float* ln_g   = (const float*)d_in[3];
  const float* ln_b   = (const float*)d_in[4];
  const float* q_bias = (const float*)d_in[5];
  const float* v_bias = (const float*)d_in[6];
  const float* scale  = (const float*)d_in[7];
  const float* cpb_w0 = (const float*)d_in[8];
  const float* cpb_b0 = (const float*)d_in[9];
  const float* cpb_w1 = (const float*)d_in[10];
  const float* w_proj = (const float*)d_in[11];
  float* out = (float*)d_out;

  char* ws = (char*)d_ws;
  const size_t PRE  = (size_t)NPIX * 768 * 2;     // qkv_pre; reused for attn_out
  const size_t QKVW = (size_t)131072 * 768 * 2;   // window-padded qkv
  ushort* pre    = (ushort*)ws;
  ushort* qkvw   = (ushort*)(ws + PRE);
  ushort* xb     = (ushort*)(ws + PRE);           // bf16 x, parked in qkvw region
                                                  // (dead once convw writes qkvw)
  ushort* aoutb  = pre;
  ushort* wqkvT  = (ushort*)(ws + PRE + QKVW);
  ushort* wprojT = (ushort*)(ws + PRE + QKVW + (size_t)768 * 256 * 2);
  float*  cpbtmp = (float*)(ws + PRE + QKVW + (size_t)768 * 256 * 2 + (size_t)256 * 256 * 2);
  float*  biasT  = (float*)(ws + PRE + QKVW + (size_t)768 * 256 * 2 + (size_t)256 * 256 * 2 + 8192);

  k_cvt_wT<<<768, 256, 0, stream>>>(w_qkv, wqkvT, 768, 256);
  k_cvt_wT<<<256, 256, 0, stream>>>(w_proj, wprojT, 256, 256);
  k_cpb1<<<57, 256, 0, stream>>>(cpb_w0, cpb_b0, cpb_w1, cpbtmp);
  k_cpb2<<<128, 256, 0, stream>>>(cpbtmp, biasT);
  k_cvt_x<<<2048, 256, 0, stream>>>(x, xb, NPIX * 256 / 8);
  k_gemm<0, 6><<<5958, 256, 0, stream>>>(xb, wqkvT, pre, NPIX, 768);
  k_convw<<<4536, 256, 0, stream>>>(pre, w_dw, qkvw);
  k_ln2<<<31752, 256, 0, stream>>>(qkvw, ln_g, ln_b, q_bias, v_bias, scale);
  k_attn<<<4096, 256, 0, stream>>>(qkvw, biasT, aoutb);
  k_gemm<1, 2><<<1986, 256, 0, stream>>>(aoutb, wprojT, out, NPIX, 256);
}